// Round 5
// baseline (382.441 us; speedup 1.0000x reference)
//
#include <hip/hip_runtime.h>
#include <cmath>

#define DIM_  1024
#define NH_   16
#define DH_   64
#define NL_   3
#define NK_   4
#define B_    2
#define T_    2048
#define OFFC_ (NH_ * NL_ * NK_)   // 192
#define KDIM  1024

typedef __attribute__((ext_vector_type(8))) __bf16 bf16x8;
typedef __attribute__((ext_vector_type(4))) float f32x4;

__device__ __forceinline__ unsigned short f2bf(float f) {
  unsigned u = __float_as_uint(f);
  u += 0x7FFFu + ((u >> 16) & 1u);
  return (unsigned short)(u >> 16);
}
__device__ __forceinline__ float bf2f(unsigned short s) {
  return __uint_as_float((unsigned)s << 16);
}

__device__ __forceinline__ void glds16(const void* g, void* l) {
  __builtin_amdgcn_global_load_lds((const __attribute__((address_space(1))) void*)g,
                                   (__attribute__((address_space(3))) void*)l, 16, 0, 0);
}

// ---------------- x fp32 -> xcat bf16 [row][hi(1024) | lo(1024) | hi(1024)] ----------------
__global__ void cvt2_kernel(const float* __restrict__ x, unsigned short* __restrict__ xcat) {
  int i = blockIdx.x * blockDim.x + threadIdx.x;
  if (i >= 4096 * 256) return;
  int row = i >> 8, c = (i & 255) * 4;
  float4 a = ((const float4*)x)[i];
  ushort4 hi, lo;
  hi.x = f2bf(a.x); hi.y = f2bf(a.y); hi.z = f2bf(a.z); hi.w = f2bf(a.w);
  lo.x = f2bf(a.x - bf2f(hi.x)); lo.y = f2bf(a.y - bf2f(hi.y));
  lo.z = f2bf(a.z - bf2f(hi.z)); lo.w = f2bf(a.w - bf2f(hi.w));
  size_t base = (size_t)row * 3072 + c;
  *(ushort4*)(xcat + base) = hi;
  *(ushort4*)(xcat + base + 1024) = lo;
  *(ushort4*)(xcat + base + 2048) = hi;
}

// ---------------- downsample level1: pair average -> bf16 ----------------
__global__ void ds1_kernel(const float* __restrict__ x, unsigned short* __restrict__ f1) {
  int i = blockIdx.x * blockDim.x + threadIdx.x;
  const int C4 = DIM_ / 4;
  if (i >= B_ * (T_ / 2) * C4) return;
  int c4 = i % C4, t = (i / C4) % (T_ / 2), b = i / (C4 * (T_ / 2));
  const float4* r0 = (const float4*)(x + (size_t)(b * T_ + 2 * t) * DIM_) + c4;
  const float4* r1 = r0 + C4;
  float4 a = *r0, c = *r1;
  ushort4 o;
  o.x = f2bf(0.5f * (a.x + c.x)); o.y = f2bf(0.5f * (a.y + c.y));
  o.z = f2bf(0.5f * (a.z + c.z)); o.w = f2bf(0.5f * (a.w + c.w));
  ((ushort4*)(f1 + (size_t)(b * (T_ / 2) + t) * DIM_))[c4] = o;
}

// ---------------- downsample level2: avg of 4 (pairwise) -> bf16 ----------------
__global__ void ds2_kernel(const float* __restrict__ x, unsigned short* __restrict__ f2) {
  int i = blockIdx.x * blockDim.x + threadIdx.x;
  const int C4 = DIM_ / 4;
  if (i >= B_ * (T_ / 4) * C4) return;
  int c4 = i % C4, t = (i / C4) % (T_ / 4), b = i / (C4 * (T_ / 4));
  const float4* r0 = (const float4*)(x + (size_t)(b * T_ + 4 * t) * DIM_) + c4;
  const float4* r1 = r0 + C4;
  const float4* r2 = r1 + C4;
  const float4* r3 = r2 + C4;
  float4 a = *r0, bb = *r1, c = *r2, d = *r3;
  ushort4 o;
  o.x = f2bf(0.5f * (0.5f * (a.x + bb.x) + 0.5f * (c.x + d.x)));
  o.y = f2bf(0.5f * (0.5f * (a.y + bb.y) + 0.5f * (c.y + d.y)));
  o.z = f2bf(0.5f * (0.5f * (a.z + bb.z) + 0.5f * (c.z + d.z)));
  o.w = f2bf(0.5f * (0.5f * (a.w + bb.w) + 0.5f * (c.w + d.w)));
  ((ushort4*)(f2 + (size_t)(b * (T_ / 4) + t) * DIM_))[c4] = o;
}

// ---------------- weight transpose + cast: W fp32 [K][N=1024] -> Wt bf16 [N][K] ----------------
__global__ void wtrans_kernel(const float* __restrict__ W, unsigned short* __restrict__ Wt) {
  __shared__ float tile[32][33];
  int k0 = blockIdx.x * 32, n0 = blockIdx.y * 32;
  int tx = threadIdx.x, ty = threadIdx.y;   // (32, 8)
#pragma unroll
  for (int r = 0; r < 32; r += 8)
    tile[ty + r][tx] = W[(size_t)(k0 + ty + r) * KDIM + n0 + tx];
  __syncthreads();
#pragma unroll
  for (int r = 0; r < 32; r += 8)
    Wt[(size_t)(n0 + ty + r) * KDIM + k0 + tx] = f2bf(tile[tx][ty + r]);
}

// ---------------- Woff fp32 [1024][192] -> Wofft [256][3072] = [hi|hi|lo], rows>=192 zero ----------------
__global__ void wtrans_off_kernel(const float* __restrict__ W, unsigned short* __restrict__ Wt) {
  __shared__ float tile[32][33];
  int k0 = blockIdx.x * 32, n0 = blockIdx.y * 32;
  int tx = threadIdx.x, ty = threadIdx.y;   // (32, 8)
#pragma unroll
  for (int r = 0; r < 32; r += 8) {
    int nn = n0 + tx;
    tile[ty + r][tx] = (nn < OFFC_) ? W[(size_t)(k0 + ty + r) * OFFC_ + nn] : 0.0f;
  }
  __syncthreads();
#pragma unroll
  for (int r = 0; r < 32; r += 8) {
    float v = tile[tx][ty + r];
    unsigned short hi = f2bf(v);
    unsigned short lo = f2bf(v - bf2f(hi));
    size_t n = (size_t)(n0 + ty + r);
    Wt[n * 3072 + k0 + tx] = hi;
    Wt[n * 3072 + 1024 + k0 + tx] = hi;
    Wt[n * 3072 + 2048 + k0 + tx] = lo;
  }
}

// ---------------- bias concat: [bq|bk|bv|bo] ----------------
__global__ void bias_cat_kernel(const float* bq, const float* bk, const float* bv,
                                const float* bo, float* bc) {
  int i = blockIdx.x * blockDim.x + threadIdx.x;
  if (i >= 4096) return;
  float v;
  if (i < 1024) v = bq[i];
  else if (i < 2048) v = bk[i - 1024];
  else if (i < 3072) v = bv[i - 2048];
  else v = bo[i - 3072];
  bc[i] = v;
}

// ---------------- boff pad to 256 ----------------
__global__ void boff_pad_kernel(const float* boff, float* bp) {
  int i = threadIdx.x;
  if (i < 256) bp[i] = (i < OFFC_) ? boff[i] : 0.0f;
}

// ---------------- bf16 MFMA GEMM: C[M,N] = A[M,K] @ Bt[N,K]^T, segmented epilogue ----------------
struct Epi {
  void* ptr[4];
  int start[4];
  int ldc[4];
  int width[4];
  int nseg;
  int bf16_mask;   // bit s: segment s stores bf16 (else fp32)
  int tanh_mask;   // bit s: tanh(.)*0.25
};

__global__ __launch_bounds__(256) void gemm_mfma_kernel(
    const unsigned short* __restrict__ A,   // [M][lda] bf16 bits
    const unsigned short* __restrict__ Bt,  // [N][K] bf16 bits
    const float* __restrict__ bias,         // [N]
    Epi epi, int M, int N, int K, int lda) {
  __shared__ __align__(16) unsigned short lds_s[8192];  // A: [0,4096), B: [4096,8192)
  unsigned short* ldsA = lds_s;
  unsigned short* ldsB = lds_s + 4096;

  const int tid = threadIdx.x;
  const int lane = tid & 63;
  const int wv = tid >> 6;
  const int wm = wv & 1, wn = wv >> 1;
  const int q = lane >> 4, jj = lane & 15;
  const int row0 = blockIdx.y * 128, col0 = blockIdx.x * 128;

  const int c0s = wv * 64 + lane;
  const int c1s = c0s + 256;
  const unsigned short* gA0 = A + (size_t)(row0 + (c0s >> 2)) * lda + (c0s & 3) * 8;
  const unsigned short* gA1 = A + (size_t)(row0 + (c1s >> 2)) * lda + (c1s & 3) * 8;
  const unsigned short* gB0 = Bt + (size_t)(col0 + (c0s >> 2)) * K + (c0s & 3) * 8;
  const unsigned short* gB1 = Bt + (size_t)(col0 + (c1s >> 2)) * K + (c1s & 3) * 8;
  unsigned short* lA0 = ldsA + (size_t)(wv * 64) * 8;
  unsigned short* lA1 = ldsA + (size_t)(256 + wv * 64) * 8;
  unsigned short* lB0 = ldsB + (size_t)(wv * 64) * 8;
  unsigned short* lB1 = ldsB + (size_t)(256 + wv * 64) * 8;

  int aoff[4], boff[4];
#pragma unroll
  for (int i = 0; i < 4; ++i) aoff[i] = ((wm * 64 + i * 16 + jj) * 4 + q) * 8;
#pragma unroll
  for (int j = 0; j < 4; ++j) boff[j] = ((wn * 64 + j * 16 + jj) * 4 + q) * 8;

  f32x4 acc[4][4] = {};

  for (int k0 = 0; k0 < K; k0 += 32) {
    glds16(gA0 + k0, lA0);
    glds16(gA1 + k0, lA1);
    glds16(gB0 + k0, lB0);
    glds16(gB1 + k0, lB1);
    __syncthreads();
    bf16x8 af[4], bfr[4];
#pragma unroll
    for (int i = 0; i < 4; ++i) af[i] = *(const bf16x8*)(ldsA + aoff[i]);
#pragma unroll
    for (int j = 0; j < 4; ++j) bfr[j] = *(const bf16x8*)(ldsB + boff[j]);
#pragma unroll
    for (int i = 0; i < 4; ++i)
#pragma unroll
      for (int j = 0; j < 4; ++j)
        acc[i][j] = __builtin_amdgcn_mfma_f32_16x16x32_bf16(af[i], bfr[j], acc[i][j], 0, 0, 0);
    __syncthreads();
  }

  int sIdx = 0;
#pragma unroll
  for (int s = 1; s < 4; ++s)
    if (s < epi.nseg && col0 >= epi.start[s]) sIdx = s;
  const int st = epi.start[sIdx], ld = epi.ldc[sIdx], wdt = epi.width[sIdx];
  const bool isBf = (epi.bf16_mask >> sIdx) & 1;
  const bool doTanh = (epi.tanh_mask >> sIdx) & 1;
  float* opf = (float*)epi.ptr[sIdx];
  unsigned short* opb = (unsigned short*)epi.ptr[sIdx];

#pragma unroll
  for (int i = 0; i < 4; ++i) {
    int rbase = row0 + wm * 64 + i * 16 + q * 4;
#pragma unroll
    for (int j = 0; j < 4; ++j) {
      int ccol = col0 + wn * 64 + j * 16 + jj;
      int lc = ccol - st;
      if (lc < wdt) {
        float bsv = bias[ccol];
#pragma unroll
        for (int p = 0; p < 4; ++p) {
          float v = acc[i][j][p] + bsv;
          if (doTanh) v = tanhf(v) * 0.25f;
          size_t oi = (size_t)(rbase + p) * ld + lc;
          if (isBf) opb[oi] = f2bf(v);
          else      opf[oi] = v;
        }
      }
    }
  }
}

// ---------------- attention: 16 lanes per (b,t,h), float4 per lane ----------------
__global__ __launch_bounds__(256) void attn_kernel(
    const unsigned short* __restrict__ qb, const float* __restrict__ off,
    const float* __restrict__ k0, const float* __restrict__ k1, const float* __restrict__ k2,
    const float* __restrict__ v0, const float* __restrict__ v1, const float* __restrict__ v2,
    unsigned short* __restrict__ out) {
  int gid = blockIdx.x * blockDim.x + threadIdx.x;
  int li  = gid & 15;
  int tup = gid >> 4;
  int h   = tup & (NH_ - 1);
  int bt  = tup >> 4;            // b*T + t
  int t   = bt & (T_ - 1);
  int b   = bt >> 11;
  const bool firstHalf = (li & 8) == 0;

  // lane li holds dims d = 4*li + j ; freq index fi = 4*(li&7)+j
  float invf[4];
#pragma unroll
  for (int j = 0; j < 4; ++j)
    invf[j] = exp2f(-(float)(4 * (li & 7) + j) * (13.287712379549449f / 32.0f));

  const int col = h * DH_ + li * 4;
  ushort4 qu = *(const ushort4*)(qb + (size_t)bt * DIM_ + col);
  float q4[4] = {bf2f(qu.x), bf2f(qu.y), bf2f(qu.z), bf2f(qu.w)};
  float qv[4];
#pragma unroll
  for (int j = 0; j < 4; ++j) {
    float pr = __shfl_xor(q4[j], 8);
    float s = __sinf((float)t * invf[j]), c = __cosf((float)t * invf[j]);
    qv[j] = firstHalf ? (q4[j] * c - pr * s) : (pr * s + q4[j] * c);
  }

  const float refp = (float)t * (1.0f / (float)(T_ - 1));
  const float* kls[3] = {k0, k1, k2};
  const float* vls[3] = {v0, v1, v2};
  const float* offp = off + (size_t)bt * OFFC_ + h * (NL_ * NK_);

  // no-max softmax: |logit| = |q.k|/8 <= ||q||||k||/8 ~ 8, exp safe in fp32
  float sum = 0.0f;
  float o4[4] = {0.0f, 0.0f, 0.0f, 0.0f};

#pragma unroll
  for (int lv = 0; lv < NL_; ++lv) {
    const int Ts = T_ >> lv;
    const float* __restrict__ kl = kls[lv];
    const float* __restrict__ vl = vls[lv];
#pragma unroll
    for (int kk = 0; kk < NK_; ++kk) {
      float ofv = offp[lv * NK_ + kk];
      float sn = fminf(fmaxf(refp + ofv, 0.0f), 1.0f);
      float idx = fminf(sn * (float)(Ts - 1), (float)(Ts - 1) - 1e-6f);
      int i0 = (int)idx;
      int i1 = min(i0 + 1, Ts - 1);
      float w1 = idx - (float)i0, w0 = 1.0f - w1;
      size_t r0 = (size_t)(b * Ts + i0) * DIM_ + col;
      size_t r1 = (size_t)(b * Ts + i1) * DIM_ + col;
      const float4 ka = *(const float4*)(kl + r0);
      const float4 kb = *(const float4*)(kl + r1);
      float kx[4] = {w0 * ka.x + w1 * kb.x, w0 * ka.y + w1 * kb.y,
                     w0 * ka.z + w1 * kb.z, w0 * ka.w + w1 * kb.w};
      float p = 0.0f;
#pragma unroll
      for (int j = 0; j < 4; ++j) {
        float pr = __shfl_xor(kx[j], 8);
        float ang = idx * invf[j];
        float s = __sinf(ang), c = __cosf(ang);
        float rk = firstHalf ? (kx[j] * c - pr * s) : (pr * s + kx[j] * c);
        p += qv[j] * rk;
      }
#pragma unroll
      for (int m = 8; m > 0; m >>= 1) p += __shfl_xor(p, m);
      float e = __expf(p * 0.125f);
      sum += e;
      const float4 va = *(const float4*)(vl + r0);
      const float4 vb = *(const float4*)(vl + r1);
      o4[0] += e * (w0 * va.x + w1 * vb.x);
      o4[1] += e * (w0 * va.y + w1 * vb.y);
      o4[2] += e * (w0 * va.z + w1 * vb.z);
      o4[3] += e * (w0 * va.w + w1 * vb.w);
    }
  }

  float r = 1.0f / sum;
  ushort4 ou;
  ou.x = f2bf(o4[0] * r); ou.y = f2bf(o4[1] * r);
  ou.z = f2bf(o4[2] * r); ou.w = f2bf(o4[3] * r);
  *(ushort4*)(out + (size_t)bt * DIM_ + col) = ou;
}

// ---------------- launch ----------------
extern "C" void kernel_launch(void* const* d_in, const int* in_sizes, int n_in,
                              void* d_out, int out_size, void* d_ws, size_t ws_size,
                              hipStream_t stream) {
  const float* x    = (const float*)d_in[0];
  const float* Wq   = (const float*)d_in[2];
  const float* bq   = (const float*)d_in[3];
  const float* Wk   = (const float*)d_in[4];
  const float* bk   = (const float*)d_in[5];
  const float* Wv   = (const float*)d_in[6];
  const float* bv   = (const float*)d_in[7];
  const float* Woff = (const float*)d_in[8];
  const float* boff = (const float*)d_in[9];
  const float* Wo   = (const float*)d_in[10];
  const float* bo   = (const float*)d_in[11];
  float* out = (float*)d_out;

  char* w = (char*)d_ws;
  auto alloc = [&](size_t bytes) { char* p = w; w += (bytes + 255) & ~(size_t)255; return p; };
  // xcat dead after gemm1/gemm_off -> ao_bf overlays it
  unsigned short* xcat  = (unsigned short*)alloc((size_t)4096 * 3072 * 2);
  unsigned short* ao_bf = xcat;
  unsigned short* f1_bf = (unsigned short*)alloc((size_t)2048 * 1024 * 2);
  unsigned short* f2_bf = (unsigned short*)alloc((size_t)1024 * 1024 * 2);  // contiguous after f1
  unsigned short* q_bf  = (unsigned short*)alloc((size_t)4096 * 1024 * 2);
  unsigned short* Btcat = (unsigned short*)alloc((size_t)4096 * 1024 * 2);
  unsigned short* Wofft = (unsigned short*)alloc((size_t)256 * 3072 * 2);
  float* biascat = (float*)alloc((size_t)4096 * 4);
  float* boffp   = (float*)alloc((size_t)256 * 4);
  float* offb = (float*)alloc((size_t)4096 * 192 * 4);
  float* k1b  = (float*)alloc((size_t)2048 * 1024 * 4);
  float* k2b  = (float*)alloc((size_t)1024 * 1024 * 4);  // contiguous after k1b
  float* v1b  = (float*)alloc((size_t)2048 * 1024 * 4);
  float* v2b  = (float*)alloc((size_t)1024 * 1024 * 4);  // contiguous after v1b
  float* k0b  = (float*)alloc((size_t)4096 * 1024 * 4);
  float* v0b  = (float*)alloc((size_t)4096 * 1024 * 4);

  dim3 b256(256);
  dim3 wtb(32, 8);
  wtrans_kernel<<<dim3(32, 32), wtb, 0, stream>>>(Wq, Btcat);
  wtrans_kernel<<<dim3(32, 32), wtb, 0, stream>>>(Wk, Btcat + (size_t)1024 * 1024);
  wtrans_kernel<<<dim3(32, 32), wtb, 0, stream>>>(Wv, Btcat + (size_t)2048 * 1024);
  wtrans_kernel<<<dim3(32, 32), wtb, 0, stream>>>(Wo, Btcat + (size_t)3072 * 1024);
  wtrans_off_kernel<<<dim3(32, 8), wtb, 0, stream>>>(Woff, Wofft);
  bias_cat_kernel<<<16, b256, 0, stream>>>(bq, bk, bv, bo, biascat);
  boff_pad_kernel<<<1, b256, 0, stream>>>(boff, boffp);
  cvt2_kernel<<<4096, b256, 0, stream>>>(x, xcat);
  ds1_kernel<<<(B_ * (T_ / 2) * (DIM_ / 4)) / 256, b256, 0, stream>>>(x, f1_bf);
  ds2_kernel<<<(B_ * (T_ / 4) * (DIM_ / 4)) / 256, b256, 0, stream>>>(x, f2_bf);

  // offset head: split-bf16 MFMA, K=3072 ([hi|lo|hi] . [Whi|Whi|Wlo]) -> ~fp32 precision
  Epi eo = {};
  eo.ptr[0] = offb; eo.start[0] = 0; eo.ldc[0] = 192; eo.width[0] = 192;
  eo.nseg = 1; eo.bf16_mask = 0; eo.tanh_mask = 1;
  gemm_mfma_kernel<<<dim3(2, 32), b256, 0, stream>>>(xcat, Wofft, boffp, eo,
                                                     4096, 256, 3072, 3072);

  // GEMM1: x @ [Wq|Wk|Wv]  (M=4096, N=3072); A = hi-segment of xcat (lda=3072)
  Epi e1 = {};
  e1.ptr[0] = q_bf; e1.ptr[1] = k0b; e1.ptr[2] = v0b;
  e1.start[0] = 0; e1.start[1] = 1024; e1.start[2] = 2048;
  e1.ldc[0] = 1024; e1.ldc[1] = 1024; e1.ldc[2] = 1024;
  e1.width[0] = 1024; e1.width[1] = 1024; e1.width[2] = 1024;
  e1.nseg = 3; e1.bf16_mask = 0x1; e1.tanh_mask = 0;
  gemm_mfma_kernel<<<dim3(24, 32), b256, 0, stream>>>(xcat, Btcat, biascat, e1,
                                                      4096, 3072, 1024, 3072);

  // GEMM2+3 merged: [f1;f2] @ [Wk|Wv]  (M=3072, N=2048); k2b/v2b contiguous after k1b/v1b
  Epi e2 = {};
  e2.ptr[0] = k1b; e2.ptr[1] = v1b;
  e2.start[0] = 0; e2.start[1] = 1024;
  e2.ldc[0] = 1024; e2.ldc[1] = 1024;
  e2.width[0] = 1024; e2.width[1] = 1024;
  e2.nseg = 2; e2.bf16_mask = 0; e2.tanh_mask = 0;
  gemm_mfma_kernel<<<dim3(16, 24), b256, 0, stream>>>(f1_bf, Btcat + (size_t)1024 * 1024,
                                                      biascat + 1024, e2, 3072, 2048, 1024, 1024);

  // attention (writes bf16 into ao_bf, which overlays the now-dead xcat)
  attn_kernel<<<(B_ * T_ * NH_ * 16) / 256, b256, 0, stream>>>(q_bf, offb, k0b, k1b, k2b,
                                                               v0b, v1b, v2b, ao_bf);

  // GEMM5: ao @ Wo  (M=4096, N=1024) -> fp32 out
  Epi e5 = {};
  e5.ptr[0] = out;
  e5.start[0] = 0; e5.ldc[0] = 1024; e5.width[0] = 1024;
  e5.nseg = 1; e5.bf16_mask = 0; e5.tanh_mask = 0;
  gemm_mfma_kernel<<<dim3(8, 32), b256, 0, stream>>>(ao_bf, Btcat + (size_t)3072 * 1024,
                                                     biascat + 3072, e5, 4096, 1024, 1024, 1024);
}

// Round 6
// 344.333 us; speedup vs baseline: 1.1107x; 1.1107x over previous
//
#include <hip/hip_runtime.h>
#include <cmath>

#define DIM_  1024
#define NH_   16
#define DH_   64
#define NL_   3
#define NK_   4
#define B_    2
#define T_    2048
#define OFFC_ (NH_ * NL_ * NK_)   // 192
#define KDIM  1024

typedef __attribute__((ext_vector_type(8))) __bf16 bf16x8;
typedef __attribute__((ext_vector_type(4))) float f32x4;

__device__ __forceinline__ unsigned short f2bf(float f) {
  unsigned u = __float_as_uint(f);
  u += 0x7FFFu + ((u >> 16) & 1u);
  return (unsigned short)(u >> 16);
}
__device__ __forceinline__ float bf2f(unsigned short s) {
  return __uint_as_float((unsigned)s << 16);
}

__device__ __forceinline__ void glds16(const void* g, void* l) {
  __builtin_amdgcn_global_load_lds((const __attribute__((address_space(1))) void*)g,
                                   (__attribute__((address_space(3))) void*)l, 16, 0, 0);
}

// ---------------- x fp32 -> xcat bf16 [row][hi(1024) | lo(1024) | hi(1024)] ----------------
__global__ void cvt2_kernel(const float* __restrict__ x, unsigned short* __restrict__ xcat) {
  int i = blockIdx.x * blockDim.x + threadIdx.x;
  if (i >= 4096 * 256) return;
  int row = i >> 8, c = (i & 255) * 4;
  float4 a = ((const float4*)x)[i];
  ushort4 hi, lo;
  hi.x = f2bf(a.x); hi.y = f2bf(a.y); hi.z = f2bf(a.z); hi.w = f2bf(a.w);
  lo.x = f2bf(a.x - bf2f(hi.x)); lo.y = f2bf(a.y - bf2f(hi.y));
  lo.z = f2bf(a.z - bf2f(hi.z)); lo.w = f2bf(a.w - bf2f(hi.w));
  size_t base = (size_t)row * 3072 + c;
  *(ushort4*)(xcat + base) = hi;
  *(ushort4*)(xcat + base + 1024) = lo;
  *(ushort4*)(xcat + base + 2048) = hi;
}

// ---------------- downsample level1: pair average -> bf16 ----------------
__global__ void ds1_kernel(const float* __restrict__ x, unsigned short* __restrict__ f1) {
  int i = blockIdx.x * blockDim.x + threadIdx.x;
  const int C4 = DIM_ / 4;
  if (i >= B_ * (T_ / 2) * C4) return;
  int c4 = i % C4, t = (i / C4) % (T_ / 2), b = i / (C4 * (T_ / 2));
  const float4* r0 = (const float4*)(x + (size_t)(b * T_ + 2 * t) * DIM_) + c4;
  const float4* r1 = r0 + C4;
  float4 a = *r0, c = *r1;
  ushort4 o;
  o.x = f2bf(0.5f * (a.x + c.x)); o.y = f2bf(0.5f * (a.y + c.y));
  o.z = f2bf(0.5f * (a.z + c.z)); o.w = f2bf(0.5f * (a.w + c.w));
  ((ushort4*)(f1 + (size_t)(b * (T_ / 2) + t) * DIM_))[c4] = o;
}

// ---------------- downsample level2: avg of 4 (pairwise) -> bf16 ----------------
__global__ void ds2_kernel(const float* __restrict__ x, unsigned short* __restrict__ f2) {
  int i = blockIdx.x * blockDim.x + threadIdx.x;
  const int C4 = DIM_ / 4;
  if (i >= B_ * (T_ / 4) * C4) return;
  int c4 = i % C4, t = (i / C4) % (T_ / 4), b = i / (C4 * (T_ / 4));
  const float4* r0 = (const float4*)(x + (size_t)(b * T_ + 4 * t) * DIM_) + c4;
  const float4* r1 = r0 + C4;
  const float4* r2 = r1 + C4;
  const float4* r3 = r2 + C4;
  float4 a = *r0, bb = *r1, c = *r2, d = *r3;
  ushort4 o;
  o.x = f2bf(0.5f * (0.5f * (a.x + bb.x) + 0.5f * (c.x + d.x)));
  o.y = f2bf(0.5f * (0.5f * (a.y + bb.y) + 0.5f * (c.y + d.y)));
  o.z = f2bf(0.5f * (0.5f * (a.z + bb.z) + 0.5f * (c.z + d.z)));
  o.w = f2bf(0.5f * (0.5f * (a.w + bb.w) + 0.5f * (c.w + d.w)));
  ((ushort4*)(f2 + (size_t)(b * (T_ / 4) + t) * DIM_))[c4] = o;
}

// ---------------- weight transpose + cast: W fp32 [K][N=1024] -> Wt bf16 [N][K] ----------------
__global__ void wtrans_kernel(const float* __restrict__ W, unsigned short* __restrict__ Wt) {
  __shared__ float tile[32][33];
  int k0 = blockIdx.x * 32, n0 = blockIdx.y * 32;
  int tx = threadIdx.x, ty = threadIdx.y;   // (32, 8)
#pragma unroll
  for (int r = 0; r < 32; r += 8)
    tile[ty + r][tx] = W[(size_t)(k0 + ty + r) * KDIM + n0 + tx];
  __syncthreads();
#pragma unroll
  for (int r = 0; r < 32; r += 8)
    Wt[(size_t)(n0 + ty + r) * KDIM + k0 + tx] = f2bf(tile[tx][ty + r]);
}

// ---------------- Woff fp32 [1024][192] -> Wofft [256][3072] = [hi|hi|lo], rows>=192 zero ----------------
__global__ void wtrans_off_kernel(const float* __restrict__ W, unsigned short* __restrict__ Wt) {
  __shared__ float tile[32][33];
  int k0 = blockIdx.x * 32, n0 = blockIdx.y * 32;
  int tx = threadIdx.x, ty = threadIdx.y;   // (32, 8)
#pragma unroll
  for (int r = 0; r < 32; r += 8) {
    int nn = n0 + tx;
    tile[ty + r][tx] = (nn < OFFC_) ? W[(size_t)(k0 + ty + r) * OFFC_ + nn] : 0.0f;
  }
  __syncthreads();
#pragma unroll
  for (int r = 0; r < 32; r += 8) {
    float v = tile[tx][ty + r];
    unsigned short hi = f2bf(v);
    unsigned short lo = f2bf(v - bf2f(hi));
    size_t n = (size_t)(n0 + ty + r);
    Wt[n * 3072 + k0 + tx] = hi;
    Wt[n * 3072 + 1024 + k0 + tx] = hi;
    Wt[n * 3072 + 2048 + k0 + tx] = lo;
  }
}

// ---------------- bias concat: [bq|bk|bv|bo] ----------------
__global__ void bias_cat_kernel(const float* bq, const float* bk, const float* bv,
                                const float* bo, float* bc) {
  int i = blockIdx.x * blockDim.x + threadIdx.x;
  if (i >= 4096) return;
  float v;
  if (i < 1024) v = bq[i];
  else if (i < 2048) v = bk[i - 1024];
  else if (i < 3072) v = bv[i - 2048];
  else v = bo[i - 3072];
  bc[i] = v;
}

// ---------------- boff pad to 256 ----------------
__global__ void boff_pad_kernel(const float* boff, float* bp) {
  int i = threadIdx.x;
  if (i < 256) bp[i] = (i < OFFC_) ? boff[i] : 0.0f;
}

// ---------------- bf16 MFMA GEMM (tile BMxBN): C = A @ Bt^T, segmented epilogue ----------------
struct Epi {
  void* ptr[4];
  int start[4];
  int ldc[4];
  int width[4];
  int nseg;
  int bf16_mask;   // bit s: segment s stores bf16 (else fp32)
  int tanh_mask;   // bit s: tanh(.)*0.25
};

template <int BM, int BN>
__global__ __launch_bounds__(256) void gemm_mfma_kernel(
    const unsigned short* __restrict__ A,   // [M][lda] bf16 bits
    const unsigned short* __restrict__ Bt,  // [N][K] bf16 bits
    const float* __restrict__ bias,         // [N]
    Epi epi, int M, int N, int K, int lda) {
  constexpr int MI = BM / 32, MJ = BN / 32;          // per-wave 16x16 tiles
  constexpr int TCA = BM * 4;                        // A 16B-chunks in a K=32 tile
  constexpr int R = (BM + BN) / 64;                  // staging rounds (256 chunks each)
  __shared__ __align__(16) unsigned short lds_s[(BM + BN) * 32];
  unsigned short* ldsA = lds_s;
  unsigned short* ldsB = lds_s + BM * 32;

  const int tid = threadIdx.x;
  const int lane = tid & 63;
  const int wv = tid >> 6;
  const int wm = wv & 1, wn = wv >> 1;
  const int q = lane >> 4, jj = lane & 15;
  const int row0 = blockIdx.y * BM, col0 = blockIdx.x * BN;

  const unsigned short* gP[R];
  unsigned short* lP[R];
#pragma unroll
  for (int r = 0; r < R; ++r) {
    int c = r * 256 + tid;
    if (c < TCA) {
      gP[r] = A + (size_t)(row0 + (c >> 2)) * lda + (c & 3) * 8;
      lP[r] = ldsA + c * 8;
    } else {
      int c2 = c - TCA;
      gP[r] = Bt + (size_t)(col0 + (c2 >> 2)) * K + (c2 & 3) * 8;
      lP[r] = ldsB + c2 * 8;
    }
  }

  int aoff[MI], boff[MJ];
#pragma unroll
  for (int i = 0; i < MI; ++i) aoff[i] = ((wm * (BM / 2) + i * 16 + jj) * 4 + q) * 8;
#pragma unroll
  for (int j = 0; j < MJ; ++j) boff[j] = ((wn * (BN / 2) + j * 16 + jj) * 4 + q) * 8;

  f32x4 acc[MI][MJ] = {};

  for (int k0 = 0; k0 < K; k0 += 32) {
#pragma unroll
    for (int r = 0; r < R; ++r) glds16(gP[r] + k0, lP[r]);
    __syncthreads();
    bf16x8 af[MI], bfr[MJ];
#pragma unroll
    for (int i = 0; i < MI; ++i) af[i] = *(const bf16x8*)(ldsA + aoff[i]);
#pragma unroll
    for (int j = 0; j < MJ; ++j) bfr[j] = *(const bf16x8*)(ldsB + boff[j]);
#pragma unroll
    for (int i = 0; i < MI; ++i)
#pragma unroll
      for (int j = 0; j < MJ; ++j)
        acc[i][j] = __builtin_amdgcn_mfma_f32_16x16x32_bf16(af[i], bfr[j], acc[i][j], 0, 0, 0);
    __syncthreads();
  }

  int sIdx = 0;
#pragma unroll
  for (int s = 1; s < 4; ++s)
    if (s < epi.nseg && col0 >= epi.start[s]) sIdx = s;
  const int st = epi.start[sIdx], ld = epi.ldc[sIdx], wdt = epi.width[sIdx];
  const bool isBf = (epi.bf16_mask >> sIdx) & 1;
  const bool doTanh = (epi.tanh_mask >> sIdx) & 1;
  float* opf = (float*)epi.ptr[sIdx];
  unsigned short* opb = (unsigned short*)epi.ptr[sIdx];

#pragma unroll
  for (int i = 0; i < MI; ++i) {
    int rbase = row0 + wm * (BM / 2) + i * 16 + q * 4;
#pragma unroll
    for (int j = 0; j < MJ; ++j) {
      int ccol = col0 + wn * (BN / 2) + j * 16 + jj;
      int lc = ccol - st;
      if (lc < wdt) {
        float bsv = bias[ccol];
#pragma unroll
        for (int p = 0; p < 4; ++p) {
          float v = acc[i][j][p] + bsv;
          if (doTanh) v = tanhf(v) * 0.25f;
          size_t oi = (size_t)(rbase + p) * ld + lc;
          if (isBf) opb[oi] = f2bf(v);
          else      opf[oi] = v;
        }
      }
    }
  }
}

// ---------------- attention: 16 lanes per (b,t,h), float4 per lane ----------------
__global__ __launch_bounds__(256) void attn_kernel(
    const unsigned short* __restrict__ qb, const float* __restrict__ off,
    const float* __restrict__ k0, const float* __restrict__ k1, const float* __restrict__ k2,
    const float* __restrict__ v0, const float* __restrict__ v1, const float* __restrict__ v2,
    unsigned short* __restrict__ out) {
  int gid = blockIdx.x * blockDim.x + threadIdx.x;
  int li  = gid & 15;
  int tup = gid >> 4;
  int h   = tup & (NH_ - 1);
  int bt  = tup >> 4;            // b*T + t
  int t   = bt & (T_ - 1);
  int b   = bt >> 11;
  const bool firstHalf = (li & 8) == 0;

  // lane li holds dims d = 4*li + j ; freq index fi = 4*(li&7)+j
  float invf[4];
#pragma unroll
  for (int j = 0; j < 4; ++j)
    invf[j] = exp2f(-(float)(4 * (li & 7) + j) * (13.287712379549449f / 32.0f));

  const int col = h * DH_ + li * 4;
  ushort4 qu = *(const ushort4*)(qb + (size_t)bt * DIM_ + col);
  float q4[4] = {bf2f(qu.x), bf2f(qu.y), bf2f(qu.z), bf2f(qu.w)};
  float qv[4];
#pragma unroll
  for (int j = 0; j < 4; ++j) {
    float pr = __shfl_xor(q4[j], 8);
    float s = __sinf((float)t * invf[j]), c = __cosf((float)t * invf[j]);
    qv[j] = firstHalf ? (q4[j] * c - pr * s) : (pr * s + q4[j] * c);
  }

  const float refp = (float)t * (1.0f / (float)(T_ - 1));
  const float* kls[3] = {k0, k1, k2};
  const float* vls[3] = {v0, v1, v2};
  const float* offp = off + (size_t)bt * OFFC_ + h * (NL_ * NK_);

  // no-max softmax: |logit| = |q.k|/8 <= ||q||||k||/8 ~ 8, exp safe in fp32
  float sum = 0.0f;
  float o4[4] = {0.0f, 0.0f, 0.0f, 0.0f};

#pragma unroll
  for (int lv = 0; lv < NL_; ++lv) {
    const int Ts = T_ >> lv;
    const float* __restrict__ kl = kls[lv];
    const float* __restrict__ vl = vls[lv];
#pragma unroll
    for (int kk = 0; kk < NK_; ++kk) {
      float ofv = offp[lv * NK_ + kk];
      float sn = fminf(fmaxf(refp + ofv, 0.0f), 1.0f);
      float idx = fminf(sn * (float)(Ts - 1), (float)(Ts - 1) - 1e-6f);
      int i0 = (int)idx;
      int i1 = min(i0 + 1, Ts - 1);
      float w1 = idx - (float)i0, w0 = 1.0f - w1;
      size_t r0 = (size_t)(b * Ts + i0) * DIM_ + col;
      size_t r1 = (size_t)(b * Ts + i1) * DIM_ + col;
      const float4 ka = *(const float4*)(kl + r0);
      const float4 kb = *(const float4*)(kl + r1);
      float kx[4] = {w0 * ka.x + w1 * kb.x, w0 * ka.y + w1 * kb.y,
                     w0 * ka.z + w1 * kb.z, w0 * ka.w + w1 * kb.w};
      float p = 0.0f;
#pragma unroll
      for (int j = 0; j < 4; ++j) {
        float pr = __shfl_xor(kx[j], 8);
        float ang = idx * invf[j];
        float s = __sinf(ang), c = __cosf(ang);
        float rk = firstHalf ? (kx[j] * c - pr * s) : (pr * s + kx[j] * c);
        p += qv[j] * rk;
      }
#pragma unroll
      for (int m = 8; m > 0; m >>= 1) p += __shfl_xor(p, m);
      float e = __expf(p * 0.125f);
      sum += e;
      const float4 va = *(const float4*)(vl + r0);
      const float4 vb = *(const float4*)(vl + r1);
      o4[0] += e * (w0 * va.x + w1 * vb.x);
      o4[1] += e * (w0 * va.y + w1 * vb.y);
      o4[2] += e * (w0 * va.z + w1 * vb.z);
      o4[3] += e * (w0 * va.w + w1 * vb.w);
    }
  }

  float r = 1.0f / sum;
  ushort4 ou;
  ou.x = f2bf(o4[0] * r); ou.y = f2bf(o4[1] * r);
  ou.z = f2bf(o4[2] * r); ou.w = f2bf(o4[3] * r);
  *(ushort4*)(out + (size_t)bt * DIM_ + col) = ou;
}

// ---------------- launch ----------------
extern "C" void kernel_launch(void* const* d_in, const int* in_sizes, int n_in,
                              void* d_out, int out_size, void* d_ws, size_t ws_size,
                              hipStream_t stream) {
  const float* x    = (const float*)d_in[0];
  const float* Wq   = (const float*)d_in[2];
  const float* bq   = (const float*)d_in[3];
  const float* Wk   = (const float*)d_in[4];
  const float* bk   = (const float*)d_in[5];
  const float* Wv   = (const float*)d_in[6];
  const float* bv   = (const float*)d_in[7];
  const float* Woff = (const float*)d_in[8];
  const float* boff = (const float*)d_in[9];
  const float* Wo   = (const float*)d_in[10];
  const float* bo   = (const float*)d_in[11];
  float* out = (float*)d_out;

  char* w = (char*)d_ws;
  auto alloc = [&](size_t bytes) { char* p = w; w += (bytes + 255) & ~(size_t)255; return p; };
  // xcat dead after gemm1/gemm_off -> ao_bf overlays it
  unsigned short* xcat  = (unsigned short*)alloc((size_t)4096 * 3072 * 2);
  unsigned short* ao_bf = xcat;
  unsigned short* f1_bf = (unsigned short*)alloc((size_t)2048 * 1024 * 2);
  unsigned short* f2_bf = (unsigned short*)alloc((size_t)1024 * 1024 * 2);  // contiguous after f1
  unsigned short* q_bf  = (unsigned short*)alloc((size_t)4096 * 1024 * 2);
  unsigned short* Btcat = (unsigned short*)alloc((size_t)4096 * 1024 * 2);
  unsigned short* Wofft = (unsigned short*)alloc((size_t)256 * 3072 * 2);
  float* biascat = (float*)alloc((size_t)4096 * 4);
  float* boffp   = (float*)alloc((size_t)256 * 4);
  float* offb = (float*)alloc((size_t)4096 * 192 * 4);
  float* k1b  = (float*)alloc((size_t)2048 * 1024 * 4);
  float* k2b  = (float*)alloc((size_t)1024 * 1024 * 4);  // contiguous after k1b
  float* v1b  = (float*)alloc((size_t)2048 * 1024 * 4);
  float* v2b  = (float*)alloc((size_t)1024 * 1024 * 4);  // contiguous after v1b
  float* k0b  = (float*)alloc((size_t)4096 * 1024 * 4);
  float* v0b  = (float*)alloc((size_t)4096 * 1024 * 4);

  dim3 b256(256);
  dim3 wtb(32, 8);
  wtrans_kernel<<<dim3(32, 32), wtb, 0, stream>>>(Wq, Btcat);
  wtrans_kernel<<<dim3(32, 32), wtb, 0, stream>>>(Wk, Btcat + (size_t)1024 * 1024);
  wtrans_kernel<<<dim3(32, 32), wtb, 0, stream>>>(Wv, Btcat + (size_t)2048 * 1024);
  wtrans_kernel<<<dim3(32, 32), wtb, 0, stream>>>(Wo, Btcat + (size_t)3072 * 1024);
  wtrans_off_kernel<<<dim3(32, 8), wtb, 0, stream>>>(Woff, Wofft);
  bias_cat_kernel<<<16, b256, 0, stream>>>(bq, bk, bv, bo, biascat);
  boff_pad_kernel<<<1, b256, 0, stream>>>(boff, boffp);
  cvt2_kernel<<<4096, b256, 0, stream>>>(x, xcat);
  ds1_kernel<<<(B_ * (T_ / 2) * (DIM_ / 4)) / 256, b256, 0, stream>>>(x, f1_bf);
  ds2_kernel<<<(B_ * (T_ / 4) * (DIM_ / 4)) / 256, b256, 0, stream>>>(x, f2_bf);

  // offset head: split-bf16 MFMA, K=3072 ([hi|lo|hi] . [Whi|Whi|Wlo]) -> ~fp32 precision
  // 64x64 tiles: grid 4x64=256 blocks (was 2x32=64 @128x128 -> 2.6% occupancy, 82 us)
  Epi eo = {};
  eo.ptr[0] = offb; eo.start[0] = 0; eo.ldc[0] = 192; eo.width[0] = 192;
  eo.nseg = 1; eo.bf16_mask = 0; eo.tanh_mask = 1;
  gemm_mfma_kernel<64, 64><<<dim3(4, 64), b256, 0, stream>>>(xcat, Wofft, boffp, eo,
                                                             4096, 256, 3072, 3072);

  // GEMM1: x @ [Wq|Wk|Wv]  (M=4096, N=3072); A = hi-segment of xcat (lda=3072)
  Epi e1 = {};
  e1.ptr[0] = q_bf; e1.ptr[1] = k0b; e1.ptr[2] = v0b;
  e1.start[0] = 0; e1.start[1] = 1024; e1.start[2] = 2048;
  e1.ldc[0] = 1024; e1.ldc[1] = 1024; e1.ldc[2] = 1024;
  e1.width[0] = 1024; e1.width[1] = 1024; e1.width[2] = 1024;
  e1.nseg = 3; e1.bf16_mask = 0x1; e1.tanh_mask = 0;
  gemm_mfma_kernel<128, 128><<<dim3(24, 32), b256, 0, stream>>>(xcat, Btcat, biascat, e1,
                                                                4096, 3072, 1024, 3072);

  // GEMM2+3 merged: [f1;f2] @ [Wk|Wv]  (M=3072, N=2048); k2b/v2b contiguous after k1b/v1b
  Epi e2 = {};
  e2.ptr[0] = k1b; e2.ptr[1] = v1b;
  e2.start[0] = 0; e2.start[1] = 1024;
  e2.ldc[0] = 1024; e2.ldc[1] = 1024;
  e2.width[0] = 1024; e2.width[1] = 1024;
  e2.nseg = 2; e2.bf16_mask = 0; e2.tanh_mask = 0;
  gemm_mfma_kernel<128, 128><<<dim3(16, 24), b256, 0, stream>>>(f1_bf, Btcat + (size_t)1024 * 1024,
                                                                biascat + 1024, e2, 3072, 2048, 1024, 1024);

  // attention (writes bf16 into ao_bf, which overlays the now-dead xcat)
  attn_kernel<<<(B_ * T_ * NH_ * 16) / 256, b256, 0, stream>>>(q_bf, offb, k0b, k1b, k2b,
                                                               v0b, v1b, v2b, ao_bf);

  // GEMM5: ao @ Wo  (M=4096, N=1024) -> fp32 out
  Epi e5 = {};
  e5.ptr[0] = out;
  e5.start[0] = 0; e5.ldc[0] = 1024; e5.width[0] = 1024;
  e5.nseg = 1; e5.bf16_mask = 0; e5.tanh_mask = 0;
  gemm_mfma_kernel<128, 128><<<dim3(8, 32), b256, 0, stream>>>(ao_bf, Btcat + (size_t)3072 * 1024,
                                                               biascat + 3072, e5, 4096, 1024, 1024, 1024);
}

// Round 7
// 305.832 us; speedup vs baseline: 1.2505x; 1.1259x over previous
//
#include <hip/hip_runtime.h>
#include <cmath>

#define DIM_  1024
#define NH_   16
#define DH_   64
#define NL_   3
#define NK_   4
#define B_    2
#define T_    2048
#define OFFC_ (NH_ * NL_ * NK_)   // 192
#define KDIM  1024

typedef __attribute__((ext_vector_type(8))) __bf16 bf16x8;
typedef __attribute__((ext_vector_type(4))) float f32x4;

__device__ __forceinline__ unsigned short f2bf(float f) {
  unsigned u = __float_as_uint(f);
  u += 0x7FFFu + ((u >> 16) & 1u);
  return (unsigned short)(u >> 16);
}
__device__ __forceinline__ float bf2f(unsigned short s) {
  return __uint_as_float((unsigned)s << 16);
}

__device__ __forceinline__ void glds16(const void* g, void* l) {
  __builtin_amdgcn_global_load_lds((const __attribute__((address_space(1))) void*)g,
                                   (__attribute__((address_space(3))) void*)l, 16, 0, 0);
}

// ---------------- x fp32 -> xcat bf16 [row][hi(1024) | lo(1024) | hi(1024)] ----------------
__global__ void cvt2_kernel(const float* __restrict__ x, unsigned short* __restrict__ xcat) {
  int i = blockIdx.x * blockDim.x + threadIdx.x;
  if (i >= 4096 * 256) return;
  int row = i >> 8, c = (i & 255) * 4;
  float4 a = ((const float4*)x)[i];
  ushort4 hi, lo;
  hi.x = f2bf(a.x); hi.y = f2bf(a.y); hi.z = f2bf(a.z); hi.w = f2bf(a.w);
  lo.x = f2bf(a.x - bf2f(hi.x)); lo.y = f2bf(a.y - bf2f(hi.y));
  lo.z = f2bf(a.z - bf2f(hi.z)); lo.w = f2bf(a.w - bf2f(hi.w));
  size_t base = (size_t)row * 3072 + c;
  *(ushort4*)(xcat + base) = hi;
  *(ushort4*)(xcat + base + 1024) = lo;
  *(ushort4*)(xcat + base + 2048) = hi;
}

// ---------------- downsample level1: pair average -> bf16 ----------------
__global__ void ds1_kernel(const float* __restrict__ x, unsigned short* __restrict__ f1) {
  int i = blockIdx.x * blockDim.x + threadIdx.x;
  const int C4 = DIM_ / 4;
  if (i >= B_ * (T_ / 2) * C4) return;
  int c4 = i % C4, t = (i / C4) % (T_ / 2), b = i / (C4 * (T_ / 2));
  const float4* r0 = (const float4*)(x + (size_t)(b * T_ + 2 * t) * DIM_) + c4;
  const float4* r1 = r0 + C4;
  float4 a = *r0, c = *r1;
  ushort4 o;
  o.x = f2bf(0.5f * (a.x + c.x)); o.y = f2bf(0.5f * (a.y + c.y));
  o.z = f2bf(0.5f * (a.z + c.z)); o.w = f2bf(0.5f * (a.w + c.w));
  ((ushort4*)(f1 + (size_t)(b * (T_ / 2) + t) * DIM_))[c4] = o;
}

// ---------------- downsample level2: avg of 4 (pairwise) -> bf16 ----------------
__global__ void ds2_kernel(const float* __restrict__ x, unsigned short* __restrict__ f2) {
  int i = blockIdx.x * blockDim.x + threadIdx.x;
  const int C4 = DIM_ / 4;
  if (i >= B_ * (T_ / 4) * C4) return;
  int c4 = i % C4, t = (i / C4) % (T_ / 4), b = i / (C4 * (T_ / 4));
  const float4* r0 = (const float4*)(x + (size_t)(b * T_ + 4 * t) * DIM_) + c4;
  const float4* r1 = r0 + C4;
  const float4* r2 = r1 + C4;
  const float4* r3 = r2 + C4;
  float4 a = *r0, bb = *r1, c = *r2, d = *r3;
  ushort4 o;
  o.x = f2bf(0.5f * (0.5f * (a.x + bb.x) + 0.5f * (c.x + d.x)));
  o.y = f2bf(0.5f * (0.5f * (a.y + bb.y) + 0.5f * (c.y + d.y)));
  o.z = f2bf(0.5f * (0.5f * (a.z + bb.z) + 0.5f * (c.z + d.z)));
  o.w = f2bf(0.5f * (0.5f * (a.w + bb.w) + 0.5f * (c.w + d.w)));
  ((ushort4*)(f2 + (size_t)(b * (T_ / 4) + t) * DIM_))[c4] = o;
}

// ---------------- weight transpose + cast: W fp32 [K][N=1024] -> Wt bf16 [N][K] ----------------
__global__ void wtrans_kernel(const float* __restrict__ W, unsigned short* __restrict__ Wt) {
  __shared__ float tile[32][33];
  int k0 = blockIdx.x * 32, n0 = blockIdx.y * 32;
  int tx = threadIdx.x, ty = threadIdx.y;   // (32, 8)
#pragma unroll
  for (int r = 0; r < 32; r += 8)
    tile[ty + r][tx] = W[(size_t)(k0 + ty + r) * KDIM + n0 + tx];
  __syncthreads();
#pragma unroll
  for (int r = 0; r < 32; r += 8)
    Wt[(size_t)(n0 + ty + r) * KDIM + k0 + tx] = f2bf(tile[tx][ty + r]);
}

// ---------------- Woff fp32 [1024][192] -> Wofft [256][3072] = [hi|hi|lo], rows>=192 zero ----------------
__global__ void wtrans_off_kernel(const float* __restrict__ W, unsigned short* __restrict__ Wt) {
  __shared__ float tile[32][33];
  int k0 = blockIdx.x * 32, n0 = blockIdx.y * 32;
  int tx = threadIdx.x, ty = threadIdx.y;   // (32, 8)
#pragma unroll
  for (int r = 0; r < 32; r += 8) {
    int nn = n0 + tx;
    tile[ty + r][tx] = (nn < OFFC_) ? W[(size_t)(k0 + ty + r) * OFFC_ + nn] : 0.0f;
  }
  __syncthreads();
#pragma unroll
  for (int r = 0; r < 32; r += 8) {
    float v = tile[tx][ty + r];
    unsigned short hi = f2bf(v);
    unsigned short lo = f2bf(v - bf2f(hi));
    size_t n = (size_t)(n0 + ty + r);
    Wt[n * 3072 + k0 + tx] = hi;
    Wt[n * 3072 + 1024 + k0 + tx] = hi;
    Wt[n * 3072 + 2048 + k0 + tx] = lo;
  }
}

// ---------------- bias concat: [bq|bk|bv|bo] ----------------
__global__ void bias_cat_kernel(const float* bq, const float* bk, const float* bv,
                                const float* bo, float* bc) {
  int i = blockIdx.x * blockDim.x + threadIdx.x;
  if (i >= 4096) return;
  float v;
  if (i < 1024) v = bq[i];
  else if (i < 2048) v = bk[i - 1024];
  else if (i < 3072) v = bv[i - 2048];
  else v = bo[i - 3072];
  bc[i] = v;
}

// ---------------- boff pad to 256 ----------------
__global__ void boff_pad_kernel(const float* boff, float* bp) {
  int i = threadIdx.x;
  if (i < 256) bp[i] = (i < OFFC_) ? boff[i] : 0.0f;
}

// ---------------- bf16 MFMA GEMM (tile BMxBN): C = A @ Bt^T, segmented epilogue ----------------
struct Epi {
  void* ptr[4];
  int start[4];
  int ldc[4];
  int width[4];
  int nseg;
  int bf16_mask;   // bit s: segment s stores bf16 (else fp32)
  int tanh_mask;   // bit s: tanh(.)*0.25
};

template <int BM, int BN>
__global__ __launch_bounds__(256) void gemm_mfma_kernel(
    const unsigned short* __restrict__ A,   // [M][lda] bf16 bits
    const unsigned short* __restrict__ Bt,  // [N][K] bf16 bits
    const float* __restrict__ bias,         // [N]
    Epi epi, int M, int N, int K, int lda) {
  constexpr int MI = BM / 32, MJ = BN / 32;          // per-wave 16x16 tiles
  constexpr int TCA = BM * 4;                        // A 16B-chunks in a K=32 tile
  constexpr int R = (BM + BN) / 64;                  // staging rounds (256 chunks each)
  __shared__ __align__(16) unsigned short lds_s[(BM + BN) * 32];
  unsigned short* ldsA = lds_s;
  unsigned short* ldsB = lds_s + BM * 32;

  const int tid = threadIdx.x;
  const int lane = tid & 63;
  const int wv = tid >> 6;
  const int wm = wv & 1, wn = wv >> 1;
  const int q = lane >> 4, jj = lane & 15;
  const int row0 = blockIdx.y * BM, col0 = blockIdx.x * BN;

  const unsigned short* gP[R];
  unsigned short* lP[R];
#pragma unroll
  for (int r = 0; r < R; ++r) {
    int c = r * 256 + tid;
    if (c < TCA) {
      gP[r] = A + (size_t)(row0 + (c >> 2)) * lda + (c & 3) * 8;
      lP[r] = ldsA + c * 8;
    } else {
      int c2 = c - TCA;
      gP[r] = Bt + (size_t)(col0 + (c2 >> 2)) * K + (c2 & 3) * 8;
      lP[r] = ldsB + c2 * 8;
    }
  }

  int aoff[MI], boff[MJ];
#pragma unroll
  for (int i = 0; i < MI; ++i) aoff[i] = ((wm * (BM / 2) + i * 16 + jj) * 4 + q) * 8;
#pragma unroll
  for (int j = 0; j < MJ; ++j) boff[j] = ((wn * (BN / 2) + j * 16 + jj) * 4 + q) * 8;

  f32x4 acc[MI][MJ] = {};

  for (int k0 = 0; k0 < K; k0 += 32) {
#pragma unroll
    for (int r = 0; r < R; ++r) glds16(gP[r] + k0, lP[r]);
    __syncthreads();
    bf16x8 af[MI], bfr[MJ];
#pragma unroll
    for (int i = 0; i < MI; ++i) af[i] = *(const bf16x8*)(ldsA + aoff[i]);
#pragma unroll
    for (int j = 0; j < MJ; ++j) bfr[j] = *(const bf16x8*)(ldsB + boff[j]);
#pragma unroll
    for (int i = 0; i < MI; ++i)
#pragma unroll
      for (int j = 0; j < MJ; ++j)
        acc[i][j] = __builtin_amdgcn_mfma_f32_16x16x32_bf16(af[i], bfr[j], acc[i][j], 0, 0, 0);
    __syncthreads();
  }

  int sIdx = 0;
#pragma unroll
  for (int s = 1; s < 4; ++s)
    if (s < epi.nseg && col0 >= epi.start[s]) sIdx = s;
  const int st = epi.start[sIdx], ld = epi.ldc[sIdx], wdt = epi.width[sIdx];
  const bool isBf = (epi.bf16_mask >> sIdx) & 1;
  const bool doTanh = (epi.tanh_mask >> sIdx) & 1;
  float* opf = (float*)epi.ptr[sIdx];
  unsigned short* opb = (unsigned short*)epi.ptr[sIdx];

#pragma unroll
  for (int i = 0; i < MI; ++i) {
    int rbase = row0 + wm * (BM / 2) + i * 16 + q * 4;
#pragma unroll
    for (int j = 0; j < MJ; ++j) {
      int ccol = col0 + wn * (BN / 2) + j * 16 + jj;
      int lc = ccol - st;
      if (lc < wdt) {
        float bsv = bias[ccol];
#pragma unroll
        for (int p = 0; p < 4; ++p) {
          float v = acc[i][j][p] + bsv;
          if (doTanh) v = tanhf(v) * 0.25f;
          size_t oi = (size_t)(rbase + p) * ld + lc;
          if (isBf) opb[oi] = f2bf(v);
          else      opf[oi] = v;
        }
      }
    }
  }
}

// ---------------- attention: 16 lanes per (b,t,h); bf16 k/v; XCD-swizzled blocks ----------------
__global__ __launch_bounds__(256) void attn_kernel(
    const unsigned short* __restrict__ qb, const float* __restrict__ off,
    const unsigned short* __restrict__ k0, const unsigned short* __restrict__ k1,
    const unsigned short* __restrict__ k2,
    const unsigned short* __restrict__ v0, const unsigned short* __restrict__ v1,
    const unsigned short* __restrict__ v2,
    unsigned short* __restrict__ out) {
  // XCD-contiguous swizzle: HW round-robins blockIdx across 8 XCDs; remap so each
  // XCD sees a contiguous bt range (shrinks per-XCD-L2 sampling window ~4x).
  const int nb8 = gridDim.x >> 3;
  int sb = ((blockIdx.x & 7) * nb8) + (blockIdx.x >> 3);
  int gid = sb * 256 + threadIdx.x;
  int li  = gid & 15;
  int tup = gid >> 4;
  int h   = tup & (NH_ - 1);
  int bt  = tup >> 4;            // b*T + t
  int t   = bt & (T_ - 1);
  int b   = bt >> 11;
  const bool firstHalf = (li & 8) == 0;

  float invf[4];
#pragma unroll
  for (int j = 0; j < 4; ++j)
    invf[j] = exp2f(-(float)(4 * (li & 7) + j) * (13.287712379549449f / 32.0f));

  const int col = h * DH_ + li * 4;
  ushort4 qu = *(const ushort4*)(qb + (size_t)bt * DIM_ + col);
  float q4[4] = {bf2f(qu.x), bf2f(qu.y), bf2f(qu.z), bf2f(qu.w)};
  float qv[4];
#pragma unroll
  for (int j = 0; j < 4; ++j) {
    float pr = __shfl_xor(q4[j], 8);
    float s = __sinf((float)t * invf[j]), c = __cosf((float)t * invf[j]);
    qv[j] = firstHalf ? (q4[j] * c - pr * s) : (pr * s + q4[j] * c);
  }

  const float refp = (float)t * (1.0f / (float)(T_ - 1));
  const unsigned short* kls[3] = {k0, k1, k2};
  const unsigned short* vls[3] = {v0, v1, v2};
  const float* offp = off + (size_t)bt * OFFC_ + h * (NL_ * NK_);

  // no-max softmax: |logit| <= ~10, exp safe in fp32
  float sum = 0.0f;
  float o4[4] = {0.0f, 0.0f, 0.0f, 0.0f};

#pragma unroll
  for (int lv = 0; lv < NL_; ++lv) {
    const int Ts = T_ >> lv;
    const unsigned short* __restrict__ kl = kls[lv];
    const unsigned short* __restrict__ vl = vls[lv];
#pragma unroll
    for (int kk = 0; kk < NK_; ++kk) {
      float ofv = offp[lv * NK_ + kk];
      float sn = fminf(fmaxf(refp + ofv, 0.0f), 1.0f);
      float idx = fminf(sn * (float)(Ts - 1), (float)(Ts - 1) - 1e-6f);
      int i0 = (int)idx;
      int i1 = min(i0 + 1, Ts - 1);
      float w1 = idx - (float)i0, w0 = 1.0f - w1;
      size_t r0 = (size_t)(b * Ts + i0) * DIM_ + col;
      size_t r1 = (size_t)(b * Ts + i1) * DIM_ + col;
      const ushort4 ka = *(const ushort4*)(kl + r0);
      const ushort4 kb = *(const ushort4*)(kl + r1);
      float kx[4] = {w0 * bf2f(ka.x) + w1 * bf2f(kb.x), w0 * bf2f(ka.y) + w1 * bf2f(kb.y),
                     w0 * bf2f(ka.z) + w1 * bf2f(kb.z), w0 * bf2f(ka.w) + w1 * bf2f(kb.w)};
      float p = 0.0f;
#pragma unroll
      for (int j = 0; j < 4; ++j) {
        float pr = __shfl_xor(kx[j], 8);
        float ang = idx * invf[j];
        float s = __sinf(ang), c = __cosf(ang);
        float rk = firstHalf ? (kx[j] * c - pr * s) : (pr * s + kx[j] * c);
        p += qv[j] * rk;
      }
#pragma unroll
      for (int m = 8; m > 0; m >>= 1) p += __shfl_xor(p, m);
      float e = __expf(p * 0.125f);
      sum += e;
      const ushort4 va = *(const ushort4*)(vl + r0);
      const ushort4 vb = *(const ushort4*)(vl + r1);
      o4[0] += e * (w0 * bf2f(va.x) + w1 * bf2f(vb.x));
      o4[1] += e * (w0 * bf2f(va.y) + w1 * bf2f(vb.y));
      o4[2] += e * (w0 * bf2f(va.z) + w1 * bf2f(vb.z));
      o4[3] += e * (w0 * bf2f(va.w) + w1 * bf2f(vb.w));
    }
  }

  float r = 1.0f / sum;
  ushort4 ou;
  ou.x = f2bf(o4[0] * r); ou.y = f2bf(o4[1] * r);
  ou.z = f2bf(o4[2] * r); ou.w = f2bf(o4[3] * r);
  *(ushort4*)(out + (size_t)bt * DIM_ + col) = ou;
}

// ---------------- launch ----------------
extern "C" void kernel_launch(void* const* d_in, const int* in_sizes, int n_in,
                              void* d_out, int out_size, void* d_ws, size_t ws_size,
                              hipStream_t stream) {
  const float* x    = (const float*)d_in[0];
  const float* Wq   = (const float*)d_in[2];
  const float* bq   = (const float*)d_in[3];
  const float* Wk   = (const float*)d_in[4];
  const float* bk   = (const float*)d_in[5];
  const float* Wv   = (const float*)d_in[6];
  const float* bv   = (const float*)d_in[7];
  const float* Woff = (const float*)d_in[8];
  const float* boff = (const float*)d_in[9];
  const float* Wo   = (const float*)d_in[10];
  const float* bo   = (const float*)d_in[11];
  float* out = (float*)d_out;

  char* w = (char*)d_ws;
  auto alloc = [&](size_t bytes) { char* p = w; w += (bytes + 255) & ~(size_t)255; return p; };
  // xcat dead after gemm1/gemm_off -> ao_bf overlays it
  unsigned short* xcat  = (unsigned short*)alloc((size_t)4096 * 3072 * 2);
  unsigned short* ao_bf = xcat;
  unsigned short* f1_bf = (unsigned short*)alloc((size_t)2048 * 1024 * 2);
  unsigned short* f2_bf = (unsigned short*)alloc((size_t)1024 * 1024 * 2);  // contiguous after f1
  unsigned short* q_bf  = (unsigned short*)alloc((size_t)4096 * 1024 * 2);
  unsigned short* Btcat = (unsigned short*)alloc((size_t)4096 * 1024 * 2);
  unsigned short* Wofft = (unsigned short*)alloc((size_t)256 * 3072 * 2);
  float* biascat = (float*)alloc((size_t)4096 * 4);
  float* boffp   = (float*)alloc((size_t)256 * 4);
  float* offb = (float*)alloc((size_t)4096 * 192 * 4);
  // k/v pyramids in bf16 (halves attn gather bytes + GEMM write bytes)
  unsigned short* k1b = (unsigned short*)alloc((size_t)2048 * 1024 * 2);
  unsigned short* k2b = (unsigned short*)alloc((size_t)1024 * 1024 * 2);  // contiguous after k1b
  unsigned short* v1b = (unsigned short*)alloc((size_t)2048 * 1024 * 2);
  unsigned short* v2b = (unsigned short*)alloc((size_t)1024 * 1024 * 2);  // contiguous after v1b
  unsigned short* k0b = (unsigned short*)alloc((size_t)4096 * 1024 * 2);
  unsigned short* v0b = (unsigned short*)alloc((size_t)4096 * 1024 * 2);

  dim3 b256(256);
  dim3 wtb(32, 8);
  wtrans_kernel<<<dim3(32, 32), wtb, 0, stream>>>(Wq, Btcat);
  wtrans_kernel<<<dim3(32, 32), wtb, 0, stream>>>(Wk, Btcat + (size_t)1024 * 1024);
  wtrans_kernel<<<dim3(32, 32), wtb, 0, stream>>>(Wv, Btcat + (size_t)2048 * 1024);
  wtrans_kernel<<<dim3(32, 32), wtb, 0, stream>>>(Wo, Btcat + (size_t)3072 * 1024);
  wtrans_off_kernel<<<dim3(32, 8), wtb, 0, stream>>>(Woff, Wofft);
  bias_cat_kernel<<<16, b256, 0, stream>>>(bq, bk, bv, bo, biascat);
  boff_pad_kernel<<<1, b256, 0, stream>>>(boff, boffp);
  cvt2_kernel<<<4096, b256, 0, stream>>>(x, xcat);
  ds1_kernel<<<(B_ * (T_ / 2) * (DIM_ / 4)) / 256, b256, 0, stream>>>(x, f1_bf);
  ds2_kernel<<<(B_ * (T_ / 4) * (DIM_ / 4)) / 256, b256, 0, stream>>>(x, f2_bf);

  // offset head: split-bf16 MFMA, K=3072 ([hi|lo|hi] . [Whi|Whi|Wlo]) -> ~fp32 precision
  Epi eo = {};
  eo.ptr[0] = offb; eo.start[0] = 0; eo.ldc[0] = 192; eo.width[0] = 192;
  eo.nseg = 1; eo.bf16_mask = 0; eo.tanh_mask = 1;
  gemm_mfma_kernel<64, 64><<<dim3(4, 64), b256, 0, stream>>>(xcat, Wofft, boffp, eo,
                                                             4096, 256, 3072, 3072);

  // GEMM1: x @ [Wq|Wk|Wv]  (M=4096, N=3072); all outputs bf16 now
  Epi e1 = {};
  e1.ptr[0] = q_bf; e1.ptr[1] = k0b; e1.ptr[2] = v0b;
  e1.start[0] = 0; e1.start[1] = 1024; e1.start[2] = 2048;
  e1.ldc[0] = 1024; e1.ldc[1] = 1024; e1.ldc[2] = 1024;
  e1.width[0] = 1024; e1.width[1] = 1024; e1.width[2] = 1024;
  e1.nseg = 3; e1.bf16_mask = 0x7; e1.tanh_mask = 0;
  gemm_mfma_kernel<128, 128><<<dim3(24, 32), b256, 0, stream>>>(xcat, Btcat, biascat, e1,
                                                                4096, 3072, 1024, 3072);

  // GEMM2+3 merged: [f1;f2] @ [Wk|Wv]  (M=3072, N=2048) -> bf16
  Epi e2 = {};
  e2.ptr[0] = k1b; e2.ptr[1] = v1b;
  e2.start[0] = 0; e2.start[1] = 1024;
  e2.ldc[0] = 1024; e2.ldc[1] = 1024;
  e2.width[0] = 1024; e2.width[1] = 1024;
  e2.nseg = 2; e2.bf16_mask = 0x3; e2.tanh_mask = 0;
  gemm_mfma_kernel<128, 128><<<dim3(16, 24), b256, 0, stream>>>(f1_bf, Btcat + (size_t)1024 * 1024,
                                                                biascat + 1024, e2, 3072, 2048, 1024, 1024);

  // attention (bf16 k/v, XCD swizzle; writes bf16 into ao_bf overlaying dead xcat)
  attn_kernel<<<(B_ * T_ * NH_ * 16) / 256, b256, 0, stream>>>(q_bf, offb, k0b, k1b, k2b,
                                                               v0b, v1b, v2b, ao_bf);

  // GEMM5: ao @ Wo  (M=4096, N=1024) -> fp32 out
  Epi e5 = {};
  e5.ptr[0] = out;
  e5.start[0] = 0; e5.ldc[0] = 1024; e5.width[0] = 1024;
  e5.nseg = 1; e5.bf16_mask = 0; e5.tanh_mask = 0;
  gemm_mfma_kernel<128, 128><<<dim3(8, 32), b256, 0, stream>>>(ao_bf, Btcat + (size_t)3072 * 1024,
                                                               biascat + 3072, e5, 4096, 1024, 1024, 1024);
}

// Round 8
// 270.688 us; speedup vs baseline: 1.4129x; 1.1298x over previous
//
#include <hip/hip_runtime.h>
#include <cmath>

#define DIM_  1024
#define NH_   16
#define DH_   64
#define NL_   3
#define NK_   4
#define B_    2
#define T_    2048
#define OFFC_ (NH_ * NL_ * NK_)   // 192
#define KDIM  1024

typedef __attribute__((ext_vector_type(8))) __bf16 bf16x8;
typedef __attribute__((ext_vector_type(4))) float f32x4;

__device__ __forceinline__ unsigned short f2bf(float f) {
  unsigned u = __float_as_uint(f);
  u += 0x7FFFu + ((u >> 16) & 1u);
  return (unsigned short)(u >> 16);
}
__device__ __forceinline__ float bf2f(unsigned short s) {
  return __uint_as_float((unsigned)s << 16);
}
__device__ __forceinline__ void glds16(const void* g, void* l) {
  __builtin_amdgcn_global_load_lds((const __attribute__((address_space(1))) void*)g,
                                   (__attribute__((address_space(3))) void*)l, 16, 0, 0);
}
// LDS chunk swizzle (involution): spreads fragment-read bank groups 8-way -> 2-way
__device__ __forceinline__ int swz(int c) { return c ^ ((c >> 3) & 7); }

// ---------------- x fp32 -> xcat bf16 [row][hi(1024) | lo(1024) | hi(1024)] ----------------
__global__ void cvt2_kernel(const float* __restrict__ x, unsigned short* __restrict__ xcat) {
  int i = blockIdx.x * blockDim.x + threadIdx.x;
  if (i >= 4096 * 256) return;
  int row = i >> 8, c = (i & 255) * 4;
  float4 a = ((const float4*)x)[i];
  ushort4 hi, lo;
  hi.x = f2bf(a.x); hi.y = f2bf(a.y); hi.z = f2bf(a.z); hi.w = f2bf(a.w);
  lo.x = f2bf(a.x - bf2f(hi.x)); lo.y = f2bf(a.y - bf2f(hi.y));
  lo.z = f2bf(a.z - bf2f(hi.z)); lo.w = f2bf(a.w - bf2f(hi.w));
  size_t base = (size_t)row * 3072 + c;
  *(ushort4*)(xcat + base) = hi;
  *(ushort4*)(xcat + base + 1024) = lo;
  *(ushort4*)(xcat + base + 2048) = hi;
}

// ---------------- downsample level1: pair average -> bf16 ----------------
__global__ void ds1_kernel(const float* __restrict__ x, unsigned short* __restrict__ f1) {
  int i = blockIdx.x * blockDim.x + threadIdx.x;
  const int C4 = DIM_ / 4;
  if (i >= B_ * (T_ / 2) * C4) return;
  int c4 = i % C4, t = (i / C4) % (T_ / 2), b = i / (C4 * (T_ / 2));
  const float4* r0 = (const float4*)(x + (size_t)(b * T_ + 2 * t) * DIM_) + c4;
  const float4* r1 = r0 + C4;
  float4 a = *r0, c = *r1;
  ushort4 o;
  o.x = f2bf(0.5f * (a.x + c.x)); o.y = f2bf(0.5f * (a.y + c.y));
  o.z = f2bf(0.5f * (a.z + c.z)); o.w = f2bf(0.5f * (a.w + c.w));
  ((ushort4*)(f1 + (size_t)(b * (T_ / 2) + t) * DIM_))[c4] = o;
}

// ---------------- downsample level2: avg of 4 (pairwise) -> bf16 ----------------
__global__ void ds2_kernel(const float* __restrict__ x, unsigned short* __restrict__ f2) {
  int i = blockIdx.x * blockDim.x + threadIdx.x;
  const int C4 = DIM_ / 4;
  if (i >= B_ * (T_ / 4) * C4) return;
  int c4 = i % C4, t = (i / C4) % (T_ / 4), b = i / (C4 * (T_ / 4));
  const float4* r0 = (const float4*)(x + (size_t)(b * T_ + 4 * t) * DIM_) + c4;
  const float4* r1 = r0 + C4;
  const float4* r2 = r1 + C4;
  const float4* r3 = r2 + C4;
  float4 a = *r0, bb = *r1, c = *r2, d = *r3;
  ushort4 o;
  o.x = f2bf(0.5f * (0.5f * (a.x + bb.x) + 0.5f * (c.x + d.x)));
  o.y = f2bf(0.5f * (0.5f * (a.y + bb.y) + 0.5f * (c.y + d.y)));
  o.z = f2bf(0.5f * (0.5f * (a.z + bb.z) + 0.5f * (c.z + d.z)));
  o.w = f2bf(0.5f * (0.5f * (a.w + bb.w) + 0.5f * (c.w + d.w)));
  ((ushort4*)(f2 + (size_t)(b * (T_ / 4) + t) * DIM_))[c4] = o;
}

// ---------------- 4x weight transpose+cast in one launch (z-routed) ----------------
__global__ void wtrans4_kernel(const float* __restrict__ W0, const float* __restrict__ W1,
                               const float* __restrict__ W2, const float* __restrict__ W3,
                               unsigned short* __restrict__ Wt) {
  const float* Ws = (blockIdx.z == 0) ? W0 : (blockIdx.z == 1) ? W1 : (blockIdx.z == 2) ? W2 : W3;
  unsigned short* Wd = Wt + (size_t)blockIdx.z * 1024 * 1024;
  __shared__ float tile[32][33];
  int k0 = blockIdx.x * 32, n0 = blockIdx.y * 32;
  int tx = threadIdx.x, ty = threadIdx.y;   // (32, 8)
#pragma unroll
  for (int r = 0; r < 32; r += 8)
    tile[ty + r][tx] = Ws[(size_t)(k0 + ty + r) * KDIM + n0 + tx];
  __syncthreads();
#pragma unroll
  for (int r = 0; r < 32; r += 8)
    Wd[(size_t)(n0 + ty + r) * KDIM + k0 + tx] = f2bf(tile[tx][ty + r]);
}

// ---------------- Woff fp32 [1024][192] -> Wofft [256][3072] = [hi|hi|lo], rows>=192 zero ----------------
__global__ void wtrans_off_kernel(const float* __restrict__ W, unsigned short* __restrict__ Wt) {
  __shared__ float tile[32][33];
  int k0 = blockIdx.x * 32, n0 = blockIdx.y * 32;
  int tx = threadIdx.x, ty = threadIdx.y;   // (32, 8)
#pragma unroll
  for (int r = 0; r < 32; r += 8) {
    int nn = n0 + tx;
    tile[ty + r][tx] = (nn < OFFC_) ? W[(size_t)(k0 + ty + r) * OFFC_ + nn] : 0.0f;
  }
  __syncthreads();
#pragma unroll
  for (int r = 0; r < 32; r += 8) {
    float v = tile[tx][ty + r];
    unsigned short hi = f2bf(v);
    unsigned short lo = f2bf(v - bf2f(hi));
    size_t n = (size_t)(n0 + ty + r);
    Wt[n * 3072 + k0 + tx] = hi;
    Wt[n * 3072 + 1024 + k0 + tx] = hi;
    Wt[n * 3072 + 2048 + k0 + tx] = lo;
  }
}

// ---------------- bias concat [bq|bk|bv|bo] + padded boff, one launch ----------------
__global__ void bias_all_kernel(const float* bq, const float* bk, const float* bv,
                                const float* bo, const float* boff,
                                float* bc, float* bp) {
  int i = blockIdx.x * blockDim.x + threadIdx.x;
  if (i < 4096) {
    float v;
    if (i < 1024) v = bq[i];
    else if (i < 2048) v = bk[i - 1024];
    else if (i < 3072) v = bv[i - 2048];
    else v = bo[i - 3072];
    bc[i] = v;
  } else if (i < 4352) {
    int j = i - 4096;
    bp[j] = (j < OFFC_) ? boff[j] : 0.0f;
  }
}

// ---------------- grouped bf16 MFMA GEMM, 128x128 tile, segmented epilogue ----------------
struct Epi {
  void* ptr[4];
  int start[4];
  int ldc[4];
  int width[4];
  int nseg;
  int bf16_mask;   // bit s: segment s stores bf16 (else fp32)
  int tanh_mask;   // bit s: tanh(.)*0.25
};
struct Group {
  const unsigned short* A;   // [M][lda] bf16 bits
  const unsigned short* Bt;  // [N][K] bf16 bits
  const float* bias;         // [N]
  Epi epi;
  int K, lda;
  int blk0, nbx;             // first flat block id, N/128
};
struct GArgs { Group g[3]; int ng; };

__global__ __launch_bounds__(256) void gemm_grouped_kernel(GArgs ga) {
  constexpr int BM = 128, BN = 128;
  constexpr int MI = 4, MJ = 4;
  constexpr int TCA = BM * 4;            // 512 A-chunks per K=32 tile
  __shared__ __align__(16) unsigned short lds_s[(BM + BN) * 32];  // 16 KB

  int gi = 0;
#pragma unroll
  for (int s = 1; s < 3; ++s)
    if (s < ga.ng && (int)blockIdx.x >= ga.g[s].blk0) gi = s;
  const unsigned short* A  = ga.g[gi].A;
  const unsigned short* Bt = ga.g[gi].Bt;
  const float* bias = ga.g[gi].bias;
  const int K = ga.g[gi].K, lda = ga.g[gi].lda;
  const int bflat = blockIdx.x - ga.g[gi].blk0;
  const int nbx = ga.g[gi].nbx;
  const int row0 = (bflat / nbx) * BM, col0 = (bflat % nbx) * BN;

  const int tid = threadIdx.x;
  const int lane = tid & 63;
  const int wv = tid >> 6;
  const int wm = wv & 1, wn = wv >> 1;
  const int q = lane >> 4, jj = lane & 15;

  // staging: HW writes LDS at (wave-uniform base + lane*16); we permute the GLOBAL
  // source so LDS slot l holds chunk swz(l)  (swz is an involution)
  const unsigned short* gP[4];
  unsigned short* lP[4];
#pragma unroll
  for (int r = 0; r < 4; ++r) {
    int l = r * 256 + tid;
    int c = swz(l);            // stays within A/B partition (swz touches low 3 bits only)
    lP[r] = lds_s + l * 8;
    if (c < TCA)
      gP[r] = A + (size_t)(row0 + (c >> 2)) * lda + (c & 3) * 8;
    else {
      int c2 = c - TCA;
      gP[r] = Bt + (size_t)(col0 + (c2 >> 2)) * K + (c2 & 3) * 8;
    }
  }

  int aoff[MI], boff[MJ];
#pragma unroll
  for (int i = 0; i < MI; ++i) aoff[i] = swz((wm * 64 + i * 16 + jj) * 4 + q) * 8;
#pragma unroll
  for (int j = 0; j < MJ; ++j) boff[j] = (TCA + swz((wn * 64 + j * 16 + jj) * 4 + q)) * 8;

  f32x4 acc[MI][MJ] = {};

  for (int k0 = 0; k0 < K; k0 += 32) {
#pragma unroll
    for (int r = 0; r < 4; ++r) glds16(gP[r] + k0, lP[r]);
    __syncthreads();
    bf16x8 af[MI], bfr[MJ];
#pragma unroll
    for (int i = 0; i < MI; ++i) af[i] = *(const bf16x8*)(lds_s + aoff[i]);
#pragma unroll
    for (int j = 0; j < MJ; ++j) bfr[j] = *(const bf16x8*)(lds_s + boff[j]);
#pragma unroll
    for (int i = 0; i < MI; ++i)
#pragma unroll
      for (int j = 0; j < MJ; ++j)
        acc[i][j] = __builtin_amdgcn_mfma_f32_16x16x32_bf16(af[i], bfr[j], acc[i][j], 0, 0, 0);
    __syncthreads();
  }

  const Epi& epi = ga.g[gi].epi;
  int sIdx = 0;
#pragma unroll
  for (int s = 1; s < 4; ++s)
    if (s < epi.nseg && col0 >= epi.start[s]) sIdx = s;
  const int st = epi.start[sIdx], ld = epi.ldc[sIdx], wdt = epi.width[sIdx];
  const bool isBf = (epi.bf16_mask >> sIdx) & 1;
  const bool doTanh = (epi.tanh_mask >> sIdx) & 1;
  float* opf = (float*)epi.ptr[sIdx];
  unsigned short* opb = (unsigned short*)epi.ptr[sIdx];

#pragma unroll
  for (int i = 0; i < MI; ++i) {
    int rbase = row0 + wm * 64 + i * 16 + q * 4;
#pragma unroll
    for (int j = 0; j < MJ; ++j) {
      int ccol = col0 + wn * 64 + j * 16 + jj;
      int lc = ccol - st;
      if (lc < wdt) {
        float bsv = bias[ccol];
#pragma unroll
        for (int p = 0; p < 4; ++p) {
          float v = acc[i][j][p] + bsv;
          if (doTanh) v = tanhf(v) * 0.25f;
          size_t oi = (size_t)(rbase + p) * ld + lc;
          if (isBf) opb[oi] = f2bf(v);
          else      opf[oi] = v;
        }
      }
    }
  }
}

// ---------------- attention: 16 lanes per (b,t,h); bf16 k/v; XCD-swizzled blocks ----------------
__global__ __launch_bounds__(256) void attn_kernel(
    const unsigned short* __restrict__ qb, const float* __restrict__ off,
    const unsigned short* __restrict__ k0, const unsigned short* __restrict__ k1,
    const unsigned short* __restrict__ k2,
    const unsigned short* __restrict__ v0, const unsigned short* __restrict__ v1,
    const unsigned short* __restrict__ v2,
    unsigned short* __restrict__ out) {
  const int nb8 = gridDim.x >> 3;
  int sb = ((blockIdx.x & 7) * nb8) + (blockIdx.x >> 3);
  int gid = sb * 256 + threadIdx.x;
  int li  = gid & 15;
  int tup = gid >> 4;
  int h   = tup & (NH_ - 1);
  int bt  = tup >> 4;            // b*T + t
  int t   = bt & (T_ - 1);
  int b   = bt >> 11;
  const bool firstHalf = (li & 8) == 0;

  float invf[4];
#pragma unroll
  for (int j = 0; j < 4; ++j)
    invf[j] = exp2f(-(float)(4 * (li & 7) + j) * (13.287712379549449f / 32.0f));

  const int col = h * DH_ + li * 4;
  ushort4 qu = *(const ushort4*)(qb + (size_t)bt * DIM_ + col);
  float q4[4] = {bf2f(qu.x), bf2f(qu.y), bf2f(qu.z), bf2f(qu.w)};
  float qv[4];
#pragma unroll
  for (int j = 0; j < 4; ++j) {
    float pr = __shfl_xor(q4[j], 8);
    float s = __sinf((float)t * invf[j]), c = __cosf((float)t * invf[j]);
    qv[j] = firstHalf ? (q4[j] * c - pr * s) : (pr * s + q4[j] * c);
  }

  const float refp = (float)t * (1.0f / (float)(T_ - 1));
  const unsigned short* kls[3] = {k0, k1, k2};
  const unsigned short* vls[3] = {v0, v1, v2};
  const float* offp = off + (size_t)bt * OFFC_ + h * (NL_ * NK_);

  float sum = 0.0f;
  float o4[4] = {0.0f, 0.0f, 0.0f, 0.0f};

#pragma unroll
  for (int lv = 0; lv < NL_; ++lv) {
    const int Ts = T_ >> lv;
    const unsigned short* __restrict__ kl = kls[lv];
    const unsigned short* __restrict__ vl = vls[lv];
#pragma unroll
    for (int kk = 0; kk < NK_; ++kk) {
      float ofv = offp[lv * NK_ + kk];
      float sn = fminf(fmaxf(refp + ofv, 0.0f), 1.0f);
      float idx = fminf(sn * (float)(Ts - 1), (float)(Ts - 1) - 1e-6f);
      int i0 = (int)idx;
      int i1 = min(i0 + 1, Ts - 1);
      float w1 = idx - (float)i0, w0 = 1.0f - w1;
      size_t r0 = (size_t)(b * Ts + i0) * DIM_ + col;
      size_t r1 = (size_t)(b * Ts + i1) * DIM_ + col;
      const ushort4 ka = *(const ushort4*)(kl + r0);
      const ushort4 kb = *(const ushort4*)(kl + r1);
      float kx[4] = {w0 * bf2f(ka.x) + w1 * bf2f(kb.x), w0 * bf2f(ka.y) + w1 * bf2f(kb.y),
                     w0 * bf2f(ka.z) + w1 * bf2f(kb.z), w0 * bf2f(ka.w) + w1 * bf2f(kb.w)};
      float p = 0.0f;
#pragma unroll
      for (int j = 0; j < 4; ++j) {
        float pr = __shfl_xor(kx[j], 8);
        float ang = idx * invf[j];
        float s = __sinf(ang), c = __cosf(ang);
        float rk = firstHalf ? (kx[j] * c - pr * s) : (pr * s + kx[j] * c);
        p += qv[j] * rk;
      }
#pragma unroll
      for (int m = 8; m > 0; m >>= 1) p += __shfl_xor(p, m);
      float e = __expf(p * 0.125f);
      sum += e;
      const ushort4 va = *(const ushort4*)(vl + r0);
      const ushort4 vb = *(const ushort4*)(vl + r1);
      o4[0] += e * (w0 * bf2f(va.x) + w1 * bf2f(vb.x));
      o4[1] += e * (w0 * bf2f(va.y) + w1 * bf2f(vb.y));
      o4[2] += e * (w0 * bf2f(va.z) + w1 * bf2f(vb.z));
      o4[3] += e * (w0 * bf2f(va.w) + w1 * bf2f(vb.w));
    }
  }

  float r = 1.0f / sum;
  ushort4 ou;
  ou.x = f2bf(o4[0] * r); ou.y = f2bf(o4[1] * r);
  ou.z = f2bf(o4[2] * r); ou.w = f2bf(o4[3] * r);
  *(ushort4*)(out + (size_t)bt * DIM_ + col) = ou;
}

// ---------------- launch ----------------
extern "C" void kernel_launch(void* const* d_in, const int* in_sizes, int n_in,
                              void* d_out, int out_size, void* d_ws, size_t ws_size,
                              hipStream_t stream) {
  const float* x    = (const float*)d_in[0];
  const float* Wq   = (const float*)d_in[2];
  const float* bq   = (const float*)d_in[3];
  const float* Wk   = (const float*)d_in[4];
  const float* bk   = (const float*)d_in[5];
  const float* Wv   = (const float*)d_in[6];
  const float* bv   = (const float*)d_in[7];
  const float* Woff = (const float*)d_in[8];
  const float* boff = (const float*)d_in[9];
  const float* Wo   = (const float*)d_in[10];
  const float* bo   = (const float*)d_in[11];
  float* out = (float*)d_out;

  char* w = (char*)d_ws;
  auto alloc = [&](size_t bytes) { char* p = w; w += (bytes + 255) & ~(size_t)255; return p; };
  unsigned short* xcat  = (unsigned short*)alloc((size_t)4096 * 3072 * 2);
  unsigned short* ao_bf = xcat;   // overlays dead xcat after GEMMs
  unsigned short* f1_bf = (unsigned short*)alloc((size_t)2048 * 1024 * 2);
  unsigned short* f2_bf = (unsigned short*)alloc((size_t)1024 * 1024 * 2);  // contiguous after f1
  unsigned short* q_bf  = (unsigned short*)alloc((size_t)4096 * 1024 * 2);
  unsigned short* Btcat = (unsigned short*)alloc((size_t)4096 * 1024 * 2);
  unsigned short* Wofft = (unsigned short*)alloc((size_t)256 * 3072 * 2);
  float* biascat = (float*)alloc((size_t)4096 * 4);
  float* boffp   = (float*)alloc((size_t)256 * 4);
  float* offb = (float*)alloc((size_t)4096 * 192 * 4);
  unsigned short* k1b = (unsigned short*)alloc((size_t)2048 * 1024 * 2);
  unsigned short* k2b = (unsigned short*)alloc((size_t)1024 * 1024 * 2);  // contiguous after k1b
  unsigned short* v1b = (unsigned short*)alloc((size_t)2048 * 1024 * 2);
  unsigned short* v2b = (unsigned short*)alloc((size_t)1024 * 1024 * 2);  // contiguous after v1b
  unsigned short* k0b = (unsigned short*)alloc((size_t)4096 * 1024 * 2);
  unsigned short* v0b = (unsigned short*)alloc((size_t)4096 * 1024 * 2);

  dim3 b256(256);
  dim3 wtb(32, 8);
  wtrans4_kernel<<<dim3(32, 32, 4), wtb, 0, stream>>>(Wq, Wk, Wv, Wo, Btcat);
  wtrans_off_kernel<<<dim3(32, 8), wtb, 0, stream>>>(Woff, Wofft);
  bias_all_kernel<<<17, b256, 0, stream>>>(bq, bk, bv, bo, boff, biascat, boffp);
  cvt2_kernel<<<4096, b256, 0, stream>>>(x, xcat);
  ds1_kernel<<<(B_ * (T_ / 2) * (DIM_ / 4)) / 256, b256, 0, stream>>>(x, f1_bf);
  ds2_kernel<<<(B_ * (T_ / 4) * (DIM_ / 4)) / 256, b256, 0, stream>>>(x, f2_bf);

  // Grouped GEMM: [offset(64 blks, K=3072, longest -> first)] + [G1(768)] + [G23(384)]
  GArgs ga = {};
  // g0: offset head, M=4096 N=256(192 used) K=3072, tanh epilogue, fp32 out
  ga.g[0].A = xcat; ga.g[0].Bt = Wofft; ga.g[0].bias = boffp;
  ga.g[0].K = 3072; ga.g[0].lda = 3072; ga.g[0].blk0 = 0; ga.g[0].nbx = 2;
  ga.g[0].epi.ptr[0] = offb; ga.g[0].epi.start[0] = 0; ga.g[0].epi.ldc[0] = 192;
  ga.g[0].epi.width[0] = 192; ga.g[0].epi.nseg = 1;
  ga.g[0].epi.bf16_mask = 0; ga.g[0].epi.tanh_mask = 1;
  // g1: x @ [Wq|Wk|Wv], M=4096 N=3072 K=1024, bf16 out
  ga.g[1].A = xcat; ga.g[1].Bt = Btcat; ga.g[1].bias = biascat;
  ga.g[1].K = 1024; ga.g[1].lda = 3072; ga.g[1].blk0 = 64; ga.g[1].nbx = 24;
  ga.g[1].epi.ptr[0] = q_bf; ga.g[1].epi.ptr[1] = k0b; ga.g[1].epi.ptr[2] = v0b;
  ga.g[1].epi.start[0] = 0; ga.g[1].epi.start[1] = 1024; ga.g[1].epi.start[2] = 2048;
  ga.g[1].epi.ldc[0] = 1024; ga.g[1].epi.ldc[1] = 1024; ga.g[1].epi.ldc[2] = 1024;
  ga.g[1].epi.width[0] = 1024; ga.g[1].epi.width[1] = 1024; ga.g[1].epi.width[2] = 1024;
  ga.g[1].epi.nseg = 3; ga.g[1].epi.bf16_mask = 0x7; ga.g[1].epi.tanh_mask = 0;
  // g2: [f1;f2] @ [Wk|Wv], M=3072 N=2048 K=1024, bf16 out
  ga.g[2].A = f1_bf; ga.g[2].Bt = Btcat + (size_t)1024 * 1024; ga.g[2].bias = biascat + 1024;
  ga.g[2].K = 1024; ga.g[2].lda = 1024; ga.g[2].blk0 = 832; ga.g[2].nbx = 16;
  ga.g[2].epi.ptr[0] = k1b; ga.g[2].epi.ptr[1] = v1b;
  ga.g[2].epi.start[0] = 0; ga.g[2].epi.start[1] = 1024;
  ga.g[2].epi.ldc[0] = 1024; ga.g[2].epi.ldc[1] = 1024;
  ga.g[2].epi.width[0] = 1024; ga.g[2].epi.width[1] = 1024;
  ga.g[2].epi.nseg = 2; ga.g[2].epi.bf16_mask = 0x3; ga.g[2].epi.tanh_mask = 0;
  ga.ng = 3;
  gemm_grouped_kernel<<<1216, b256, 0, stream>>>(ga);

  // attention
  attn_kernel<<<(B_ * T_ * NH_ * 16) / 256, b256, 0, stream>>>(q_bf, offb, k0b, k1b, k2b,
                                                               v0b, v1b, v2b, ao_bf);

  // GEMM5: ao @ Wo  (M=4096, N=1024) -> fp32 out (same kernel, 1 group)
  GArgs g5 = {};
  g5.g[0].A = ao_bf; g5.g[0].Bt = Btcat + (size_t)3072 * 1024; g5.g[0].bias = biascat + 3072;
  g5.g[0].K = 1024; g5.g[0].lda = 1024; g5.g[0].blk0 = 0; g5.g[0].nbx = 8;
  g5.g[0].epi.ptr[0] = out; g5.g[0].epi.start[0] = 0; g5.g[0].epi.ldc[0] = 1024;
  g5.g[0].epi.width[0] = 1024; g5.g[0].epi.nseg = 1;
  g5.g[0].epi.bf16_mask = 0; g5.g[0].epi.tanh_mask = 0;
  g5.ng = 1;
  gemm_grouped_kernel<<<256, b256, 0, stream>>>(g5);
}

// Round 9
// 259.227 us; speedup vs baseline: 1.4753x; 1.0442x over previous
//
#include <hip/hip_runtime.h>
#include <cmath>

#define DIM_  1024
#define NH_   16
#define DH_   64
#define NL_   3
#define NK_   4
#define B_    2
#define T_    2048
#define OFFC_ (NH_ * NL_ * NK_)   // 192
#define KDIM  1024

typedef __attribute__((ext_vector_type(8))) __bf16 bf16x8;
typedef __attribute__((ext_vector_type(4))) float f32x4;

__device__ __forceinline__ unsigned short f2bf(float f) {
  unsigned u = __float_as_uint(f);
  u += 0x7FFFu + ((u >> 16) & 1u);
  return (unsigned short)(u >> 16);
}
__device__ __forceinline__ float bf2f(unsigned short s) {
  return __uint_as_float((unsigned)s << 16);
}
__device__ __forceinline__ void glds16(const void* g, void* l) {
  __builtin_amdgcn_global_load_lds((const __attribute__((address_space(1))) void*)g,
                                   (__attribute__((address_space(3))) void*)l, 16, 0, 0);
}
// LDS chunk swizzle (involution): validated r8 (SQ_LDS_BANK_CONFLICT 3.1M -> 0)
__device__ __forceinline__ int swz(int c) { return c ^ ((c >> 3) & 7); }

// ---------------- x fp32 -> xcat bf16 [row][hi(1024) | lo(1024) | hi(1024)] ----------------
__global__ void cvt2_kernel(const float* __restrict__ x, unsigned short* __restrict__ xcat) {
  int i = blockIdx.x * blockDim.x + threadIdx.x;
  if (i >= 4096 * 256) return;
  int row = i >> 8, c = (i & 255) * 4;
  float4 a = ((const float4*)x)[i];
  ushort4 hi, lo;
  hi.x = f2bf(a.x); hi.y = f2bf(a.y); hi.z = f2bf(a.z); hi.w = f2bf(a.w);
  lo.x = f2bf(a.x - bf2f(hi.x)); lo.y = f2bf(a.y - bf2f(hi.y));
  lo.z = f2bf(a.z - bf2f(hi.z)); lo.w = f2bf(a.w - bf2f(hi.w));
  size_t base = (size_t)row * 3072 + c;
  *(ushort4*)(xcat + base) = hi;
  *(ushort4*)(xcat + base + 1024) = lo;
  *(ushort4*)(xcat + base + 2048) = hi;
}

// ---------------- downsample level1: pair average -> bf16 ----------------
__global__ void ds1_kernel(const float* __restrict__ x, unsigned short* __restrict__ f1) {
  int i = blockIdx.x * blockDim.x + threadIdx.x;
  const int C4 = DIM_ / 4;
  if (i >= B_ * (T_ / 2) * C4) return;
  int c4 = i % C4, t = (i / C4) % (T_ / 2), b = i / (C4 * (T_ / 2));
  const float4* r0 = (const float4*)(x + (size_t)(b * T_ + 2 * t) * DIM_) + c4;
  const float4* r1 = r0 + C4;
  float4 a = *r0, c = *r1;
  ushort4 o;
  o.x = f2bf(0.5f * (a.x + c.x)); o.y = f2bf(0.5f * (a.y + c.y));
  o.z = f2bf(0.5f * (a.z + c.z)); o.w = f2bf(0.5f * (a.w + c.w));
  ((ushort4*)(f1 + (size_t)(b * (T_ / 2) + t) * DIM_))[c4] = o;
}

// ---------------- downsample level2: avg of 4 (pairwise) -> bf16 ----------------
__global__ void ds2_kernel(const float* __restrict__ x, unsigned short* __restrict__ f2) {
  int i = blockIdx.x * blockDim.x + threadIdx.x;
  const int C4 = DIM_ / 4;
  if (i >= B_ * (T_ / 4) * C4) return;
  int c4 = i % C4, t = (i / C4) % (T_ / 4), b = i / (C4 * (T_ / 4));
  const float4* r0 = (const float4*)(x + (size_t)(b * T_ + 4 * t) * DIM_) + c4;
  const float4* r1 = r0 + C4;
  const float4* r2 = r1 + C4;
  const float4* r3 = r2 + C4;
  float4 a = *r0, bb = *r1, c = *r2, d = *r3;
  ushort4 o;
  o.x = f2bf(0.5f * (0.5f * (a.x + bb.x) + 0.5f * (c.x + d.x)));
  o.y = f2bf(0.5f * (0.5f * (a.y + bb.y) + 0.5f * (c.y + d.y)));
  o.z = f2bf(0.5f * (0.5f * (a.z + bb.z) + 0.5f * (c.z + d.z)));
  o.w = f2bf(0.5f * (0.5f * (a.w + bb.w) + 0.5f * (c.w + d.w)));
  ((ushort4*)(f2 + (size_t)(b * (T_ / 4) + t) * DIM_))[c4] = o;
}

// ---------------- 4x weight transpose+cast in one launch (z-routed) ----------------
__global__ void wtrans4_kernel(const float* __restrict__ W0, const float* __restrict__ W1,
                               const float* __restrict__ W2, const float* __restrict__ W3,
                               unsigned short* __restrict__ Wt) {
  const float* Ws = (blockIdx.z == 0) ? W0 : (blockIdx.z == 1) ? W1 : (blockIdx.z == 2) ? W2 : W3;
  unsigned short* Wd = Wt + (size_t)blockIdx.z * 1024 * 1024;
  __shared__ float tile[32][33];
  int k0 = blockIdx.x * 32, n0 = blockIdx.y * 32;
  int tx = threadIdx.x, ty = threadIdx.y;   // (32, 8)
#pragma unroll
  for (int r = 0; r < 32; r += 8)
    tile[ty + r][tx] = Ws[(size_t)(k0 + ty + r) * KDIM + n0 + tx];
  __syncthreads();
#pragma unroll
  for (int r = 0; r < 32; r += 8)
    Wd[(size_t)(n0 + ty + r) * KDIM + k0 + tx] = f2bf(tile[tx][ty + r]);
}

// ---------------- Woff fp32 [1024][192] -> Wofft [256][3072] = [hi|hi|lo], rows>=192 zero ----------------
__global__ void wtrans_off_kernel(const float* __restrict__ W, unsigned short* __restrict__ Wt) {
  __shared__ float tile[32][33];
  int k0 = blockIdx.x * 32, n0 = blockIdx.y * 32;
  int tx = threadIdx.x, ty = threadIdx.y;   // (32, 8)
#pragma unroll
  for (int r = 0; r < 32; r += 8) {
    int nn = n0 + tx;
    tile[ty + r][tx] = (nn < OFFC_) ? W[(size_t)(k0 + ty + r) * OFFC_ + nn] : 0.0f;
  }
  __syncthreads();
#pragma unroll
  for (int r = 0; r < 32; r += 8) {
    float v = tile[tx][ty + r];
    unsigned short hi = f2bf(v);
    unsigned short lo = f2bf(v - bf2f(hi));
    size_t n = (size_t)(n0 + ty + r);
    Wt[n * 3072 + k0 + tx] = hi;
    Wt[n * 3072 + 1024 + k0 + tx] = hi;
    Wt[n * 3072 + 2048 + k0 + tx] = lo;
  }
}

// ---------------- bias concat [bq|bk|bv|bo] + padded boff, one launch ----------------
__global__ void bias_all_kernel(const float* bq, const float* bk, const float* bv,
                                const float* bo, const float* boff,
                                float* bc, float* bp) {
  int i = blockIdx.x * blockDim.x + threadIdx.x;
  if (i < 4096) {
    float v;
    if (i < 1024) v = bq[i];
    else if (i < 2048) v = bk[i - 1024];
    else if (i < 3072) v = bv[i - 2048];
    else v = bo[i - 3072];
    bc[i] = v;
  } else if (i < 4352) {
    int j = i - 4096;
    bp[j] = (j < OFFC_) ? boff[j] : 0.0f;
  }
}

// ---------------- grouped bf16 MFMA GEMM, 128x128 tile, BK=64, segmented epilogue ----------------
struct Epi {
  void* ptr[4];
  int start[4];
  int ldc[4];
  int width[4];
  int nseg;
  int bf16_mask;   // bit s: segment s stores bf16 (else fp32)
  int tanh_mask;   // bit s: tanh(.)*0.25
};
struct Group {
  const unsigned short* A;   // [M][lda] bf16 bits
  const unsigned short* Bt;  // [N][K] bf16 bits
  const float* bias;         // [N]
  Epi epi;
  int K, lda;
  int blk0, nbx;             // first flat block id, N/128
};
struct GArgs { Group g[3]; int ng; };

// BK=64: 32 MFMA per barrier (AITER density), LDS 32 KB (5 blocks/CU cap)
__global__ __launch_bounds__(256) void gemm_grouped_kernel(GArgs ga) {
  constexpr int BM = 128, BN = 128, BK = 64;
  constexpr int MI = 4, MJ = 4;
  constexpr int CPR = BK / 8;            // 16B chunks per row = 8
  constexpr int TCA = BM * CPR;          // 1024 A-chunks per K=64 tile
  constexpr int R = (BM + BN) * CPR / 256;  // 8 staging rounds
  __shared__ __align__(16) unsigned short lds_s[(BM + BN) * BK];  // 32 KB

  int gi = 0;
#pragma unroll
  for (int s = 1; s < 3; ++s)
    if (s < ga.ng && (int)blockIdx.x >= ga.g[s].blk0) gi = s;
  const unsigned short* A  = ga.g[gi].A;
  const unsigned short* Bt = ga.g[gi].Bt;
  const float* bias = ga.g[gi].bias;
  const int K = ga.g[gi].K, lda = ga.g[gi].lda;
  const int bflat = blockIdx.x - ga.g[gi].blk0;
  const int nbx = ga.g[gi].nbx;
  const int row0 = (bflat / nbx) * BM, col0 = (bflat % nbx) * BN;

  const int tid = threadIdx.x;
  const int lane = tid & 63;
  const int wv = tid >> 6;
  const int wm = wv & 1, wn = wv >> 1;
  const int q = lane >> 4, jj = lane & 15;

  // staging: LDS slot l holds chunk swz(l) (involution, keeps A/B partitions)
  const unsigned short* gP[R];
  unsigned short* lP[R];
#pragma unroll
  for (int r = 0; r < R; ++r) {
    int l = r * 256 + tid;
    int c = swz(l);
    lP[r] = lds_s + l * 8;
    if (c < TCA)
      gP[r] = A + (size_t)(row0 + (c >> 3)) * lda + (c & 7) * 8;
    else {
      int c2 = c - TCA;
      gP[r] = Bt + (size_t)(col0 + (c2 >> 3)) * K + (c2 & 7) * 8;
    }
  }

  // fragment offsets (shorts): chunk(row m, kb) = m*8 + kb, kb = h*4 + q
  int aoff[2][MI], boff[2][MJ];
#pragma unroll
  for (int h = 0; h < 2; ++h) {
#pragma unroll
    for (int i = 0; i < MI; ++i)
      aoff[h][i] = swz((wm * 64 + i * 16 + jj) * CPR + h * 4 + q) * 8;
#pragma unroll
    for (int j = 0; j < MJ; ++j)
      boff[h][j] = (TCA + swz((wn * 64 + j * 16 + jj) * CPR + h * 4 + q)) * 8;
  }

  f32x4 acc[MI][MJ] = {};

  for (int k0 = 0; k0 < K; k0 += BK) {
#pragma unroll
    for (int r = 0; r < R; ++r) glds16(gP[r] + k0, lP[r]);
    __syncthreads();
#pragma unroll
    for (int h = 0; h < 2; ++h) {
      bf16x8 af[MI], bfr[MJ];
#pragma unroll
      for (int i = 0; i < MI; ++i) af[i] = *(const bf16x8*)(lds_s + aoff[h][i]);
#pragma unroll
      for (int j = 0; j < MJ; ++j) bfr[j] = *(const bf16x8*)(lds_s + boff[h][j]);
#pragma unroll
      for (int i = 0; i < MI; ++i)
#pragma unroll
        for (int j = 0; j < MJ; ++j)
          acc[i][j] = __builtin_amdgcn_mfma_f32_16x16x32_bf16(af[i], bfr[j], acc[i][j], 0, 0, 0);
    }
    __syncthreads();
  }

  const Epi& epi = ga.g[gi].epi;
  int sIdx = 0;
#pragma unroll
  for (int s = 1; s < 4; ++s)
    if (s < epi.nseg && col0 >= epi.start[s]) sIdx = s;
  const int st = epi.start[sIdx], ld = epi.ldc[sIdx], wdt = epi.width[sIdx];
  const bool isBf = (epi.bf16_mask >> sIdx) & 1;
  const bool doTanh = (epi.tanh_mask >> sIdx) & 1;
  float* opf = (float*)epi.ptr[sIdx];
  unsigned short* opb = (unsigned short*)epi.ptr[sIdx];

#pragma unroll
  for (int i = 0; i < MI; ++i) {
    int rbase = row0 + wm * 64 + i * 16 + q * 4;
#pragma unroll
    for (int j = 0; j < MJ; ++j) {
      int ccol = col0 + wn * 64 + j * 16 + jj;
      int lc = ccol - st;
      if (lc < wdt) {
        float bsv = bias[ccol];
#pragma unroll
        for (int p = 0; p < 4; ++p) {
          float v = acc[i][j][p] + bsv;
          if (doTanh) v = tanhf(v) * 0.25f;
          size_t oi = (size_t)(rbase + p) * ld + lc;
          if (isBf) opb[oi] = f2bf(v);
          else      opf[oi] = v;
        }
      }
    }
  }
}

// ---------------- attention: 16 lanes per (b,t,h); bf16 k/v; XCD-swizzled blocks ----------------
__global__ __launch_bounds__(256) void attn_kernel(
    const unsigned short* __restrict__ qb, const float* __restrict__ off,
    const unsigned short* __restrict__ k0, const unsigned short* __restrict__ k1,
    const unsigned short* __restrict__ k2,
    const unsigned short* __restrict__ v0, const unsigned short* __restrict__ v1,
    const unsigned short* __restrict__ v2,
    unsigned short* __restrict__ out) {
  const int nb8 = gridDim.x >> 3;
  int sb = ((blockIdx.x & 7) * nb8) + (blockIdx.x >> 3);
  int gid = sb * 256 + threadIdx.x;
  int li  = gid & 15;
  int tup = gid >> 4;
  int h   = tup & (NH_ - 1);
  int bt  = tup >> 4;            // b*T + t
  int t   = bt & (T_ - 1);
  int b   = bt >> 11;
  const bool firstHalf = (li & 8) == 0;

  float invf[4];
#pragma unroll
  for (int j = 0; j < 4; ++j)
    invf[j] = exp2f(-(float)(4 * (li & 7) + j) * (13.287712379549449f / 32.0f));

  const int col = h * DH_ + li * 4;
  ushort4 qu = *(const ushort4*)(qb + (size_t)bt * DIM_ + col);
  float q4[4] = {bf2f(qu.x), bf2f(qu.y), bf2f(qu.z), bf2f(qu.w)};
  float qv[4];
#pragma unroll
  for (int j = 0; j < 4; ++j) {
    float pr = __shfl_xor(q4[j], 8);
    float s = __sinf((float)t * invf[j]), c = __cosf((float)t * invf[j]);
    qv[j] = firstHalf ? (q4[j] * c - pr * s) : (pr * s + q4[j] * c);
  }

  const float refp = (float)t * (1.0f / (float)(T_ - 1));
  const unsigned short* kls[3] = {k0, k1, k2};
  const unsigned short* vls[3] = {v0, v1, v2};
  const float* offp = off + (size_t)bt * OFFC_ + h * (NL_ * NK_);

  float sum = 0.0f;
  float o4[4] = {0.0f, 0.0f, 0.0f, 0.0f};

#pragma unroll
  for (int lv = 0; lv < NL_; ++lv) {
    const int Ts = T_ >> lv;
    const unsigned short* __restrict__ kl = kls[lv];
    const unsigned short* __restrict__ vl = vls[lv];
#pragma unroll
    for (int kk = 0; kk < NK_; ++kk) {
      float ofv = offp[lv * NK_ + kk];
      float sn = fminf(fmaxf(refp + ofv, 0.0f), 1.0f);
      float idx = fminf(sn * (float)(Ts - 1), (float)(Ts - 1) - 1e-6f);
      int i0 = (int)idx;
      int i1 = min(i0 + 1, Ts - 1);
      float w1 = idx - (float)i0, w0 = 1.0f - w1;
      size_t r0 = (size_t)(b * Ts + i0) * DIM_ + col;
      size_t r1 = (size_t)(b * Ts + i1) * DIM_ + col;
      const ushort4 ka = *(const ushort4*)(kl + r0);
      const ushort4 kb = *(const ushort4*)(kl + r1);
      float kx[4] = {w0 * bf2f(ka.x) + w1 * bf2f(kb.x), w0 * bf2f(ka.y) + w1 * bf2f(kb.y),
                     w0 * bf2f(ka.z) + w1 * bf2f(kb.z), w0 * bf2f(ka.w) + w1 * bf2f(kb.w)};
      float p = 0.0f;
#pragma unroll
      for (int j = 0; j < 4; ++j) {
        float pr = __shfl_xor(kx[j], 8);
        float ang = idx * invf[j];
        float s = __sinf(ang), c = __cosf(ang);
        float rk = firstHalf ? (kx[j] * c - pr * s) : (pr * s + kx[j] * c);
        p += qv[j] * rk;
      }
#pragma unroll
      for (int m = 8; m > 0; m >>= 1) p += __shfl_xor(p, m);
      float e = __expf(p * 0.125f);
      sum += e;
      const ushort4 va = *(const ushort4*)(vl + r0);
      const ushort4 vb = *(const ushort4*)(vl + r1);
      o4[0] += e * (w0 * bf2f(va.x) + w1 * bf2f(vb.x));
      o4[1] += e * (w0 * bf2f(va.y) + w1 * bf2f(vb.y));
      o4[2] += e * (w0 * bf2f(va.z) + w1 * bf2f(vb.z));
      o4[3] += e * (w0 * bf2f(va.w) + w1 * bf2f(vb.w));
    }
  }

  float r = 1.0f / sum;
  ushort4 ou;
  ou.x = f2bf(o4[0] * r); ou.y = f2bf(o4[1] * r);
  ou.z = f2bf(o4[2] * r); ou.w = f2bf(o4[3] * r);
  *(ushort4*)(out + (size_t)bt * DIM_ + col) = ou;
}

// ---------------- launch ----------------
extern "C" void kernel_launch(void* const* d_in, const int* in_sizes, int n_in,
                              void* d_out, int out_size, void* d_ws, size_t ws_size,
                              hipStream_t stream) {
  const float* x    = (const float*)d_in[0];
  const float* Wq   = (const float*)d_in[2];
  const float* bq   = (const float*)d_in[3];
  const float* Wk   = (const float*)d_in[4];
  const float* bk   = (const float*)d_in[5];
  const float* Wv   = (const float*)d_in[6];
  const float* bv   = (const float*)d_in[7];
  const float* Woff = (const float*)d_in[8];
  const float* boff = (const float*)d_in[9];
  const float* Wo   = (const float*)d_in[10];
  const float* bo   = (const float*)d_in[11];
  float* out = (float*)d_out;

  char* w = (char*)d_ws;
  auto alloc = [&](size_t bytes) { char* p = w; w += (bytes + 255) & ~(size_t)255; return p; };
  unsigned short* xcat  = (unsigned short*)alloc((size_t)4096 * 3072 * 2);
  unsigned short* ao_bf = xcat;   // overlays dead xcat after GEMMs
  unsigned short* f1_bf = (unsigned short*)alloc((size_t)2048 * 1024 * 2);
  unsigned short* f2_bf = (unsigned short*)alloc((size_t)1024 * 1024 * 2);  // contiguous after f1
  unsigned short* q_bf  = (unsigned short*)alloc((size_t)4096 * 1024 * 2);
  unsigned short* Btcat = (unsigned short*)alloc((size_t)4096 * 1024 * 2);
  unsigned short* Wofft = (unsigned short*)alloc((size_t)256 * 3072 * 2);
  float* biascat = (float*)alloc((size_t)4096 * 4);
  float* boffp   = (float*)alloc((size_t)256 * 4);
  float* offb = (float*)alloc((size_t)4096 * 192 * 4);
  unsigned short* k1b = (unsigned short*)alloc((size_t)2048 * 1024 * 2);
  unsigned short* k2b = (unsigned short*)alloc((size_t)1024 * 1024 * 2);  // contiguous after k1b
  unsigned short* v1b = (unsigned short*)alloc((size_t)2048 * 1024 * 2);
  unsigned short* v2b = (unsigned short*)alloc((size_t)1024 * 1024 * 2);  // contiguous after v1b
  unsigned short* k0b = (unsigned short*)alloc((size_t)4096 * 1024 * 2);
  unsigned short* v0b = (unsigned short*)alloc((size_t)4096 * 1024 * 2);

  dim3 b256(256);
  dim3 wtb(32, 8);
  wtrans4_kernel<<<dim3(32, 32, 4), wtb, 0, stream>>>(Wq, Wk, Wv, Wo, Btcat);
  wtrans_off_kernel<<<dim3(32, 8), wtb, 0, stream>>>(Woff, Wofft);
  bias_all_kernel<<<17, b256, 0, stream>>>(bq, bk, bv, bo, boff, biascat, boffp);
  cvt2_kernel<<<4096, b256, 0, stream>>>(x, xcat);
  ds1_kernel<<<(B_ * (T_ / 2) * (DIM_ / 4)) / 256, b256, 0, stream>>>(x, f1_bf);
  ds2_kernel<<<(B_ * (T_ / 4) * (DIM_ / 4)) / 256, b256, 0, stream>>>(x, f2_bf);

  // Grouped GEMM: [offset(64 blks, K=3072, longest -> first)] + [G1(768)] + [G23(384)]
  GArgs ga = {};
  ga.g[0].A = xcat; ga.g[0].Bt = Wofft; ga.g[0].bias = boffp;
  ga.g[0].K = 3072; ga.g[0].lda = 3072; ga.g[0].blk0 = 0; ga.g[0].nbx = 2;
  ga.g[0].epi.ptr[0] = offb; ga.g[0].epi.start[0] = 0; ga.g[0].epi.ldc[0] = 192;
  ga.g[0].epi.width[0] = 192; ga.g[0].epi.nseg = 1;
  ga.g[0].epi.bf16_mask = 0; ga.g[0].epi.tanh_mask = 1;
  ga.g[1].A = xcat; ga.g[1].Bt = Btcat; ga.g[1].bias = biascat;
  ga.g[1].K = 1024; ga.g[1].lda = 3072; ga.g[1].blk0 = 64; ga.g[1].nbx = 24;
  ga.g[1].epi.ptr[0] = q_bf; ga.g[1].epi.ptr[1] = k0b; ga.g[1].epi.ptr[2] = v0b;
  ga.g[1].epi.start[0] = 0; ga.g[1].epi.start[1] = 1024; ga.g[1].epi.start[2] = 2048;
  ga.g[1].epi.ldc[0] = 1024; ga.g[1].epi.ldc[1] = 1024; ga.g[1].epi.ldc[2] = 1024;
  ga.g[1].epi.width[0] = 1024; ga.g[1].epi.width[1] = 1024; ga.g[1].epi.width[2] = 1024;
  ga.g[1].epi.nseg = 3; ga.g[1].epi.bf16_mask = 0x7; ga.g[1].epi.tanh_mask = 0;
  ga.g[2].A = f1_bf; ga.g[2].Bt = Btcat + (size_t)1024 * 1024; ga.g[2].bias = biascat + 1024;
  ga.g[2].K = 1024; ga.g[2].lda = 1024; ga.g[2].blk0 = 832; ga.g[2].nbx = 16;
  ga.g[2].epi.ptr[0] = k1b; ga.g[2].epi.ptr[1] = v1b;
  ga.g[2].epi.start[0] = 0; ga.g[2].epi.start[1] = 1024;
  ga.g[2].epi.ldc[0] = 1024; ga.g[2].epi.ldc[1] = 1024;
  ga.g[2].epi.width[0] = 1024; ga.g[2].epi.width[1] = 1024;
  ga.g[2].epi.nseg = 2; ga.g[2].epi.bf16_mask = 0x3; ga.g[2].epi.tanh_mask = 0;
  ga.ng = 3;
  gemm_grouped_kernel<<<1216, b256, 0, stream>>>(ga);

  // attention
  attn_kernel<<<(B_ * T_ * NH_ * 16) / 256, b256, 0, stream>>>(q_bf, offb, k0b, k1b, k2b,
                                                               v0b, v1b, v2b, ao_bf);

  // GEMM5: ao @ Wo  (M=4096, N=1024) -> fp32 out
  GArgs g5 = {};
  g5.g[0].A = ao_bf; g5.g[0].Bt = Btcat + (size_t)3072 * 1024; g5.g[0].bias = biascat + 3072;
  g5.g[0].K = 1024; g5.g[0].lda = 1024; g5.g[0].blk0 = 0; g5.g[0].nbx = 8;
  g5.g[0].epi.ptr[0] = out; g5.g[0].epi.start[0] = 0; g5.g[0].epi.ldc[0] = 1024;
  g5.g[0].epi.width[0] = 1024; g5.g[0].epi.nseg = 1;
  g5.g[0].epi.bf16_mask = 0; g5.g[0].epi.tanh_mask = 0;
  g5.ng = 1;
  gemm_grouped_kernel<<<256, b256, 0, stream>>>(g5);
}

// Round 10
// 241.524 us; speedup vs baseline: 1.5835x; 1.0733x over previous
//
#include <hip/hip_runtime.h>
#include <cmath>

#define DIM_  1024
#define NH_   16
#define DH_   64
#define NL_   3
#define NK_   4
#define B_    2
#define T_    2048
#define OFFC_ (NH_ * NL_ * NK_)   // 192
#define KDIM  1024

typedef __attribute__((ext_vector_type(8))) __bf16 bf16x8;
typedef __attribute__((ext_vector_type(4))) float f32x4;

__device__ __forceinline__ unsigned short f2bf(float f) {
  unsigned u = __float_as_uint(f);
  u += 0x7FFFu + ((u >> 16) & 1u);
  return (unsigned short)(u >> 16);
}
__device__ __forceinline__ float bf2f(unsigned short s) {
  return __uint_as_float((unsigned)s << 16);
}
__device__ __forceinline__ void glds16(const void* g, void* l) {
  __builtin_amdgcn_global_load_lds((const __attribute__((address_space(1))) void*)g,
                                   (__attribute__((address_space(3))) void*)l, 16, 0, 0);
}
// LDS chunk swizzle (involution): validated r8 (SQ_LDS_BANK_CONFLICT 3.1M -> 0)
__device__ __forceinline__ int swz(int c) { return c ^ ((c >> 3) & 7); }

// ================= mega-prep: x-cvt+downsample | biases | 5x weight transpose =================
// flat block routing: [0,1024) x-prep; [1024,1041) biases; [1041,5137) Wq/Wk/Wv/Wo; [5137,5393) Woff
__global__ __launch_bounds__(256) void prep_kernel(
    const float* __restrict__ x,
    const float* __restrict__ Wq, const float* __restrict__ Wk,
    const float* __restrict__ Wv, const float* __restrict__ Wo,
    const float* __restrict__ Woff,
    const float* __restrict__ bq, const float* __restrict__ bk,
    const float* __restrict__ bv, const float* __restrict__ bo,
    const float* __restrict__ boff,
    unsigned short* __restrict__ xcat, unsigned short* __restrict__ f1,
    unsigned short* __restrict__ f2,
    unsigned short* __restrict__ Btcat, unsigned short* __restrict__ Wofft,
    float* __restrict__ biascat, float* __restrict__ boffp) {
  __shared__ float tile[32][33];
  const int p = blockIdx.x;
  const int tid = threadIdx.x;

  if (p < 1024) {
    // ---- x prep: 4 consecutive time rows -> xcat[hi|lo|hi] x4, f1 x2, f2 x1 ----
    int b = p >> 9, t4 = p & 511;
    float4 a[4];
#pragma unroll
    for (int r = 0; r < 4; ++r)
      a[r] = *(const float4*)(x + (size_t)((b * T_ + 4 * t4 + r)) * DIM_ + tid * 4);
#pragma unroll
    for (int r = 0; r < 4; ++r) {
      ushort4 hi, lo;
      hi.x = f2bf(a[r].x); hi.y = f2bf(a[r].y); hi.z = f2bf(a[r].z); hi.w = f2bf(a[r].w);
      lo.x = f2bf(a[r].x - bf2f(hi.x)); lo.y = f2bf(a[r].y - bf2f(hi.y));
      lo.z = f2bf(a[r].z - bf2f(hi.z)); lo.w = f2bf(a[r].w - bf2f(hi.w));
      size_t base = (size_t)(b * T_ + 4 * t4 + r) * 3072 + tid * 4;
      *(ushort4*)(xcat + base) = hi;
      *(ushort4*)(xcat + base + 1024) = lo;
      *(ushort4*)(xcat + base + 2048) = hi;
    }
    float4 m01, m23;
    m01.x = 0.5f * (a[0].x + a[1].x); m01.y = 0.5f * (a[0].y + a[1].y);
    m01.z = 0.5f * (a[0].z + a[1].z); m01.w = 0.5f * (a[0].w + a[1].w);
    m23.x = 0.5f * (a[2].x + a[3].x); m23.y = 0.5f * (a[2].y + a[3].y);
    m23.z = 0.5f * (a[2].z + a[3].z); m23.w = 0.5f * (a[2].w + a[3].w);
    ushort4 o;
    o.x = f2bf(m01.x); o.y = f2bf(m01.y); o.z = f2bf(m01.z); o.w = f2bf(m01.w);
    *(ushort4*)(f1 + (size_t)(b * (T_ / 2) + 2 * t4) * DIM_ + tid * 4) = o;
    o.x = f2bf(m23.x); o.y = f2bf(m23.y); o.z = f2bf(m23.z); o.w = f2bf(m23.w);
    *(ushort4*)(f1 + (size_t)(b * (T_ / 2) + 2 * t4 + 1) * DIM_ + tid * 4) = o;
    o.x = f2bf(0.5f * (m01.x + m23.x)); o.y = f2bf(0.5f * (m01.y + m23.y));
    o.z = f2bf(0.5f * (m01.z + m23.z)); o.w = f2bf(0.5f * (m01.w + m23.w));
    *(ushort4*)(f2 + (size_t)(b * (T_ / 4) + t4) * DIM_ + tid * 4) = o;
  } else if (p < 1041) {
    // ---- biases ----
    int i = (p - 1024) * 256 + tid;
    if (i < 4096) {
      float v;
      if (i < 1024) v = bq[i];
      else if (i < 2048) v = bk[i - 1024];
      else if (i < 3072) v = bv[i - 2048];
      else v = bo[i - 3072];
      biascat[i] = v;
    } else if (i < 4352) {
      int j = i - 4096;
      boffp[j] = (j < OFFC_) ? boff[j] : 0.0f;
    }
  } else if (p < 5137) {
    // ---- Wq/Wk/Wv/Wo transpose+cast: [1024][1024] -> [N][K] bf16 ----
    int q = p - 1041;
    int z = q >> 10, q2 = q & 1023;
    const float* Ws = (z == 0) ? Wq : (z == 1) ? Wk : (z == 2) ? Wv : Wo;
    unsigned short* Wd = Btcat + (size_t)z * 1024 * 1024;
    int k0 = (q2 & 31) * 32, n0 = (q2 >> 5) * 32;
    int tx = tid & 31, ty = tid >> 5;
#pragma unroll
    for (int r = 0; r < 32; r += 8)
      tile[ty + r][tx] = Ws[(size_t)(k0 + ty + r) * KDIM + n0 + tx];
    __syncthreads();
#pragma unroll
    for (int r = 0; r < 32; r += 8)
      Wd[(size_t)(n0 + ty + r) * KDIM + k0 + tx] = f2bf(tile[tx][ty + r]);
  } else {
    // ---- Woff [1024][192] -> Wofft [256][3072] = [hi|hi|lo] ----
    int q3 = p - 5137;                 // 0..255
    int k0 = (q3 & 31) * 32, n0 = (q3 >> 5) * 32;
    int tx = tid & 31, ty = tid >> 5;
#pragma unroll
    for (int r = 0; r < 32; r += 8) {
      int nn = n0 + tx;
      tile[ty + r][tx] = (nn < OFFC_) ? Woff[(size_t)(k0 + ty + r) * OFFC_ + nn] : 0.0f;
    }
    __syncthreads();
#pragma unroll
    for (int r = 0; r < 32; r += 8) {
      float v = tile[tx][ty + r];
      unsigned short hi = f2bf(v);
      unsigned short lo = f2bf(v - bf2f(hi));
      size_t n = (size_t)(n0 + ty + r);
      Wofft[n * 3072 + k0 + tx] = hi;
      Wofft[n * 3072 + 1024 + k0 + tx] = hi;
      Wofft[n * 3072 + 2048 + k0 + tx] = lo;
    }
  }
}

// ---------------- grouped bf16 MFMA GEMM, 128x128 tile, BK=64, segmented epilogue ----------------
struct Epi {
  void* ptr[4];
  int start[4];
  int ldc[4];
  int width[4];
  int nseg;
  int bf16_mask;   // bit s: segment s stores bf16 (else fp32)
  int tanh_mask;   // bit s: tanh(.)*0.25
};
struct Group {
  const unsigned short* A;   // [M][lda] bf16 bits
  const unsigned short* Bt;  // [N][K] bf16 bits
  const float* bias;         // [N]
  Epi epi;
  int K, lda;
  int blk0, nby;             // first flat block id, M/128 (col-major block order)
};
struct GArgs { Group g[3]; int ng; };

// BK=64: 32 MFMA per barrier; col-major block order: consecutive blocks share col0
// -> A row-tiles stay L2-resident per XCD (rows = xcd mod 8 repeat across col sweep)
__global__ __launch_bounds__(256) void gemm_grouped_kernel(GArgs ga) {
  constexpr int BM = 128, BN = 128, BK = 64;
  constexpr int MI = 4, MJ = 4;
  constexpr int CPR = BK / 8;            // 16B chunks per row = 8
  constexpr int TCA = BM * CPR;          // 1024 A-chunks per K=64 tile
  constexpr int R = (BM + BN) * CPR / 256;  // 8 staging rounds
  __shared__ __align__(16) unsigned short lds_s[(BM + BN) * BK];  // 32 KB

  int gi = 0;
#pragma unroll
  for (int s = 1; s < 3; ++s)
    if (s < ga.ng && (int)blockIdx.x >= ga.g[s].blk0) gi = s;
  const unsigned short* A  = ga.g[gi].A;
  const unsigned short* Bt = ga.g[gi].Bt;
  const float* bias = ga.g[gi].bias;
  const int K = ga.g[gi].K, lda = ga.g[gi].lda;
  const int bflat = blockIdx.x - ga.g[gi].blk0;
  const int nby = ga.g[gi].nby;
  const int row0 = (bflat % nby) * BM, col0 = (bflat / nby) * BN;

  const int tid = threadIdx.x;
  const int lane = tid & 63;
  const int wv = tid >> 6;
  const int wm = wv & 1, wn = wv >> 1;
  const int q = lane >> 4, jj = lane & 15;

  // staging: LDS slot l holds chunk swz(l) (involution, keeps A/B partitions)
  const unsigned short* gP[R];
  unsigned short* lP[R];
#pragma unroll
  for (int r = 0; r < R; ++r) {
    int l = r * 256 + tid;
    int c = swz(l);
    lP[r] = lds_s + l * 8;
    if (c < TCA)
      gP[r] = A + (size_t)(row0 + (c >> 3)) * lda + (c & 7) * 8;
    else {
      int c2 = c - TCA;
      gP[r] = Bt + (size_t)(col0 + (c2 >> 3)) * K + (c2 & 7) * 8;
    }
  }

  // fragment offsets (shorts): chunk(row m, kb) = m*8 + kb, kb = h*4 + q
  int aoff[2][MI], boff[2][MJ];
#pragma unroll
  for (int h = 0; h < 2; ++h) {
#pragma unroll
    for (int i = 0; i < MI; ++i)
      aoff[h][i] = swz((wm * 64 + i * 16 + jj) * CPR + h * 4 + q) * 8;
#pragma unroll
    for (int j = 0; j < MJ; ++j)
      boff[h][j] = (TCA + swz((wn * 64 + j * 16 + jj) * CPR + h * 4 + q)) * 8;
  }

  f32x4 acc[MI][MJ] = {};

  for (int k0 = 0; k0 < K; k0 += BK) {
#pragma unroll
    for (int r = 0; r < R; ++r) glds16(gP[r] + k0, lP[r]);
    __syncthreads();
#pragma unroll
    for (int h = 0; h < 2; ++h) {
      bf16x8 af[MI], bfr[MJ];
#pragma unroll
      for (int i = 0; i < MI; ++i) af[i] = *(const bf16x8*)(lds_s + aoff[h][i]);
#pragma unroll
      for (int j = 0; j < MJ; ++j) bfr[j] = *(const bf16x8*)(lds_s + boff[h][j]);
#pragma unroll
      for (int i = 0; i < MI; ++i)
#pragma unroll
        for (int j = 0; j < MJ; ++j)
          acc[i][j] = __builtin_amdgcn_mfma_f32_16x16x32_bf16(af[i], bfr[j], acc[i][j], 0, 0, 0);
    }
    __syncthreads();
  }

  const Epi& epi = ga.g[gi].epi;
  int sIdx = 0;
#pragma unroll
  for (int s = 1; s < 4; ++s)
    if (s < epi.nseg && col0 >= epi.start[s]) sIdx = s;
  const int st = epi.start[sIdx], ld = epi.ldc[sIdx], wdt = epi.width[sIdx];
  const bool isBf = (epi.bf16_mask >> sIdx) & 1;
  const bool doTanh = (epi.tanh_mask >> sIdx) & 1;
  float* opf = (float*)epi.ptr[sIdx];
  unsigned short* opb = (unsigned short*)epi.ptr[sIdx];

#pragma unroll
  for (int i = 0; i < MI; ++i) {
    int rbase = row0 + wm * 64 + i * 16 + q * 4;
#pragma unroll
    for (int j = 0; j < MJ; ++j) {
      int ccol = col0 + wn * 64 + j * 16 + jj;
      int lc = ccol - st;
      if (lc < wdt) {
        float bsv = bias[ccol];
#pragma unroll
        for (int p = 0; p < 4; ++p) {
          float v = acc[i][j][p] + bsv;
          if (doTanh) v = tanhf(v) * 0.25f;
          size_t oi = (size_t)(rbase + p) * ld + lc;
          if (isBf) opb[oi] = f2bf(v);
          else      opf[oi] = v;
        }
      }
    }
  }
}

// ---------------- attention: 16 lanes per (b,t,h); bf16 k/v; XCD-swizzled blocks ----------------
__global__ __launch_bounds__(256) void attn_kernel(
    const unsigned short* __restrict__ qb, const float* __restrict__ off,
    const unsigned short* __restrict__ k0, const unsigned short* __restrict__ k1,
    const unsigned short* __restrict__ k2,
    const unsigned short* __restrict__ v0, const unsigned short* __restrict__ v1,
    const unsigned short* __restrict__ v2,
    unsigned short* __restrict__ out) {
  const int nb8 = gridDim.x >> 3;
  int sb = ((blockIdx.x & 7) * nb8) + (blockIdx.x >> 3);
  int gid = sb * 256 + threadIdx.x;
  int li  = gid & 15;
  int tup = gid >> 4;
  int h   = tup & (NH_ - 1);
  int bt  = tup >> 4;            // b*T + t
  int t   = bt & (T_ - 1);
  int b   = bt >> 11;
  const bool firstHalf = (li & 8) == 0;

  float invf[4];
#pragma unroll
  for (int j = 0; j < 4; ++j)
    invf[j] = exp2f(-(float)(4 * (li & 7) + j) * (13.287712379549449f / 32.0f));

  const int col = h * DH_ + li * 4;
  ushort4 qu = *(const ushort4*)(qb + (size_t)bt * DIM_ + col);
  float q4[4] = {bf2f(qu.x), bf2f(qu.y), bf2f(qu.z), bf2f(qu.w)};
  float qv[4];
#pragma unroll
  for (int j = 0; j < 4; ++j) {
    float pr = __shfl_xor(q4[j], 8);
    float s = __sinf((float)t * invf[j]), c = __cosf((float)t * invf[j]);
    qv[j] = firstHalf ? (q4[j] * c - pr * s) : (pr * s + q4[j] * c);
  }

  const float refp = (float)t * (1.0f / (float)(T_ - 1));
  const unsigned short* kls[3] = {k0, k1, k2};
  const unsigned short* vls[3] = {v0, v1, v2};
  const float* offp = off + (size_t)bt * OFFC_ + h * (NL_ * NK_);

  float sum = 0.0f;
  float o4[4] = {0.0f, 0.0f, 0.0f, 0.0f};

#pragma unroll
  for (int lv = 0; lv < NL_; ++lv) {
    const int Ts = T_ >> lv;
    const unsigned short* __restrict__ kl = kls[lv];
    const unsigned short* __restrict__ vl = vls[lv];
#pragma unroll
    for (int kk = 0; kk < NK_; ++kk) {
      float ofv = offp[lv * NK_ + kk];
      float sn = fminf(fmaxf(refp + ofv, 0.0f), 1.0f);
      float idx = fminf(sn * (float)(Ts - 1), (float)(Ts - 1) - 1e-6f);
      int i0 = (int)idx;
      int i1 = min(i0 + 1, Ts - 1);
      float w1 = idx - (float)i0, w0 = 1.0f - w1;
      size_t r0 = (size_t)(b * Ts + i0) * DIM_ + col;
      size_t r1 = (size_t)(b * Ts + i1) * DIM_ + col;
      const ushort4 ka = *(const ushort4*)(kl + r0);
      const ushort4 kb = *(const ushort4*)(kl + r1);
      float kx[4] = {w0 * bf2f(ka.x) + w1 * bf2f(kb.x), w0 * bf2f(ka.y) + w1 * bf2f(kb.y),
                     w0 * bf2f(ka.z) + w1 * bf2f(kb.z), w0 * bf2f(ka.w) + w1 * bf2f(kb.w)};
      float p = 0.0f;
#pragma unroll
      for (int j = 0; j < 4; ++j) {
        float pr = __shfl_xor(kx[j], 8);
        float ang = idx * invf[j];
        float s = __sinf(ang), c = __cosf(ang);
        float rk = firstHalf ? (kx[j] * c - pr * s) : (pr * s + kx[j] * c);
        p += qv[j] * rk;
      }
#pragma unroll
      for (int m = 8; m > 0; m >>= 1) p += __shfl_xor(p, m);
      float e = __expf(p * 0.125f);
      sum += e;
      const ushort4 va = *(const ushort4*)(vl + r0);
      const ushort4 vb = *(const ushort4*)(vl + r1);
      o4[0] += e * (w0 * bf2f(va.x) + w1 * bf2f(vb.x));
      o4[1] += e * (w0 * bf2f(va.y) + w1 * bf2f(vb.y));
      o4[2] += e * (w0 * bf2f(va.z) + w1 * bf2f(vb.z));
      o4[3] += e * (w0 * bf2f(va.w) + w1 * bf2f(vb.w));
    }
  }

  float r = 1.0f / sum;
  ushort4 ou;
  ou.x = f2bf(o4[0] * r); ou.y = f2bf(o4[1] * r);
  ou.z = f2bf(o4[2] * r); ou.w = f2bf(o4[3] * r);
  *(ushort4*)(out + (size_t)bt * DIM_ + col) = ou;
}

// ---------------- launch ----------------
extern "C" void kernel_launch(void* const* d_in, const int* in_sizes, int n_in,
                              void* d_out, int out_size, void* d_ws, size_t ws_size,
                              hipStream_t stream) {
  const float* x    = (const float*)d_in[0];
  const float* Wq   = (const float*)d_in[2];
  const float* bq   = (const float*)d_in[3];
  const float* Wk   = (const float*)d_in[4];
  const float* bk   = (const float*)d_in[5];
  const float* Wv   = (const float*)d_in[6];
  const float* bv   = (const float*)d_in[7];
  const float* Woff = (const float*)d_in[8];
  const float* boff = (const float*)d_in[9];
  const float* Wo   = (const float*)d_in[10];
  const float* bo   = (const float*)d_in[11];
  float* out = (float*)d_out;

  char* w = (char*)d_ws;
  auto alloc = [&](size_t bytes) { char* p = w; w += (bytes + 255) & ~(size_t)255; return p; };
  unsigned short* xcat  = (unsigned short*)alloc((size_t)4096 * 3072 * 2);
  unsigned short* ao_bf = xcat;   // overlays dead xcat after GEMMs
  unsigned short* f1_bf = (unsigned short*)alloc((size_t)2048 * 1024 * 2);
  unsigned short* f2_bf = (unsigned short*)alloc((size_t)1024 * 1024 * 2);  // contiguous after f1
  unsigned short* q_bf  = (unsigned short*)alloc((size_t)4096 * 1024 * 2);
  unsigned short* Btcat = (unsigned short*)alloc((size_t)4096 * 1024 * 2);
  unsigned short* Wofft = (unsigned short*)alloc((size_t)256 * 3072 * 2);
  float* biascat = (float*)alloc((size_t)4096 * 4);
  float* boffp   = (float*)alloc((size_t)256 * 4);
  float* offb = (float*)alloc((size_t)4096 * 192 * 4);
  unsigned short* k1b = (unsigned short*)alloc((size_t)2048 * 1024 * 2);
  unsigned short* k2b = (unsigned short*)alloc((size_t)1024 * 1024 * 2);  // contiguous after k1b
  unsigned short* v1b = (unsigned short*)alloc((size_t)2048 * 1024 * 2);
  unsigned short* v2b = (unsigned short*)alloc((size_t)1024 * 1024 * 2);  // contiguous after v1b
  unsigned short* k0b = (unsigned short*)alloc((size_t)4096 * 1024 * 2);
  unsigned short* v0b = (unsigned short*)alloc((size_t)4096 * 1024 * 2);

  dim3 b256(256);

  // one mega-prep dispatch (was 6): x read once; all transposes/biases fused
  prep_kernel<<<5393, b256, 0, stream>>>(x, Wq, Wk, Wv, Wo, Woff, bq, bk, bv, bo, boff,
                                         xcat, f1_bf, f2_bf, Btcat, Wofft, biascat, boffp);

  // Grouped GEMM: [offset(64 blks, K=3072, longest -> first)] + [G1(768)] + [G23(384)]
  GArgs ga = {};
  ga.g[0].A = xcat; ga.g[0].Bt = Wofft; ga.g[0].bias = boffp;
  ga.g[0].K = 3072; ga.g[0].lda = 3072; ga.g[0].blk0 = 0; ga.g[0].nby = 32;
  ga.g[0].epi.ptr[0] = offb; ga.g[0].epi.start[0] = 0; ga.g[0].epi.ldc[0] = 192;
  ga.g[0].epi.width[0] = 192; ga.g[0].epi.nseg = 1;
  ga.g[0].epi.bf16_mask = 0; ga.g[0].epi.tanh_mask = 1;
  ga.g[1].A = xcat; ga.g[1].Bt = Btcat; ga.g[1].bias = biascat;
  ga.g[1].K = 1024; ga.g[1].lda = 3072; ga.g[1].blk0 = 64; ga.g[1].nby = 32;
  ga.g[1].epi.ptr[0] = q_bf; ga.g[1].epi.ptr[1] = k0b; ga.g[1].epi.ptr[2] = v0b;
  ga.g[1].epi.start[0] = 0; ga.g[1].epi.start[1] = 1024; ga.g[1].epi.start[2] = 2048;
  ga.g[1].epi.ldc[0] = 1024; ga.g[1].epi.ldc[1] = 1024; ga.g[1].epi.ldc[2] = 1024;
  ga.g[1].epi.width[0] = 1024; ga.g[1].epi.width[1] = 1024; ga.g[1].epi.width[2] = 1024;
  ga.g[1].epi.nseg = 3; ga.g[1].epi.bf16_mask = 0x7; ga.g[1].epi.tanh_mask = 0;
  ga.g[2].A = f1_bf; ga.g[2].Bt = Btcat + (size_t)1024 * 1024; ga.g[2].bias = biascat + 1024;
  ga.g[2].K = 1024; ga.g[2].lda = 1024; ga.g[2].blk0 = 832; ga.g[2].nby = 24;
  ga.g[2].epi.ptr[0] = k1b; ga.g[2].epi.ptr[1] = v1b;
  ga.g[2].epi.start[0] = 0; ga.g[2].epi.start[1] = 1024;
  ga.g[2].epi.ldc[0] = 1024; ga.g[2].epi.ldc[1] = 1024;
  ga.g[2].epi.width[0] = 1024; ga.g[2].epi.width[1] = 1024;
  ga.g[2].epi.nseg = 2; ga.g[2].epi.bf16_mask = 0x3; ga.g[2].epi.tanh_mask = 0;
  ga.ng = 3;
  gemm_grouped_kernel<<<1216, b256, 0, stream>>>(ga);

  // attention
  attn_kernel<<<(B_ * T_ * NH_ * 16) / 256, b256, 0, stream>>>(q_bf, offb, k0b, k1b, k2b,
                                                               v0b, v1b, v2b, ao_bf);

  // GEMM5: ao @ Wo  (M=4096, N=1024) -> fp32 out
  GArgs g5 = {};
  g5.g[0].A = ao_bf; g5.g[0].Bt = Btcat + (size_t)3072 * 1024; g5.g[0].bias = biascat + 3072;
  g5.g[0].K = 1024; g5.g[0].lda = 1024; g5.g[0].blk0 = 0; g5.g[0].nby = 32;
  g5.g[0].epi.ptr[0] = out; g5.g[0].epi.start[0] = 0; g5.g[0].epi.ldc[0] = 1024;
  g5.g[0].epi.width[0] = 1024; g5.g[0].epi.nseg = 1;
  g5.g[0].epi.bf16_mask = 0; g5.g[0].epi.tanh_mask = 0;
  g5.ng = 1;
  gemm_grouped_kernel<<<256, b256, 0, stream>>>(g5);
}